// Round 2
// baseline (1937.579 us; speedup 1.0000x reference)
//
#include <hip/hip_runtime.h>
#include <cstddef>

#define DEV __device__ __forceinline__

namespace {
constexpr int BATCH = 8;
constexpr int SEQL  = 4096;
constexpr int DM    = 256;   // d_model
constexpr int DS    = 16;    // d_state
constexpr int DI    = 512;   // d_inner
constexpr int NTOK  = BATCH * SEQL;   // 32768
constexpr int TC    = 128;            // scan chunk length
constexpr int NCH   = SEQL / TC;      // 32 chunks per sequence
constexpr float EPSF = 1e-5f;

// workspace offsets (in floats)
constexpr size_t OFF_X   = 0;                                   // NTOK*DM
constexpr size_t OFF_XZ  = OFF_X   + (size_t)NTOK * DM;         // NTOK*1024 (xp | z)
constexpr size_t OFF_XC  = OFF_XZ  + (size_t)NTOK * 2 * DI;     // NTOK*DI
constexpr size_t OFF_B   = OFF_XC  + (size_t)NTOK * DI;         // NTOK*DS
constexpr size_t OFF_C   = OFF_B   + (size_t)NTOK * DS;         // NTOK*DS
constexpr size_t OFF_DTR = OFF_C   + (size_t)NTOK * DS;         // NTOK
constexpr size_t OFF_ST  = OFF_DTR + (size_t)NTOK;              // NTOK*2 (mu, rstd)
constexpr size_t OFF_HE  = OFF_ST  + (size_t)NTOK * 2;          // BATCH*DI*NCH*DS
constexpr size_t OFF_DTC = OFF_HE  + (size_t)BATCH * DI * NCH * DS; // BATCH*DI*NCH
} // namespace

DEV float sigmoidf_(float v) { return 1.0f / (1.0f + __expf(-v)); }
DEV float siluf_(float v)    { return v * sigmoidf_(v); }
DEV float softplusf_(float v) {
    // stable: max(v,0) + log1p(exp(-|v|))
    return fmaxf(v, 0.0f) + log1pf(__expf(-fabsf(v)));
}

// ---------------------------------------------------------------- input proj
__global__ void k_inproj(const float* __restrict__ z, const float* __restrict__ w,
                         const float* __restrict__ bias, float* __restrict__ x) {
    int g = blockIdx.x * 256 + threadIdx.x;     // NTOK*DM threads
    int i = g >> 8, m = g & 255;
    float4 zv = *(const float4*)(z + (size_t)i * 4);
    float4 wv = *(const float4*)(w + (size_t)m * 4);
    float r = bias[m];
    r = fmaf(zv.x, wv.x, r);
    r = fmaf(zv.y, wv.y, r);
    r = fmaf(zv.z, wv.z, r);
    r = fmaf(zv.w, wv.w, r);
    x[g] = r;
}

// ---------------------------------------------------------------- row stats
__global__ void k_stats(const float* __restrict__ x, float* __restrict__ st) {
    int lane = threadIdx.x & 63, wid = threadIdx.x >> 6;
    int i = blockIdx.x * 4 + wid;
    float4 v = *(const float4*)(x + (size_t)i * DM + lane * 4);
    float s = v.x + v.y + v.z + v.w;
    float q = v.x * v.x + v.y * v.y + v.z * v.z + v.w * v.w;
    #pragma unroll
    for (int m = 32; m; m >>= 1) { s += __shfl_xor(s, m, 64); q += __shfl_xor(q, m, 64); }
    if (lane == 0) {
        float mu = s * (1.0f / DM);
        float var = q * (1.0f / DM) - mu * mu;
        st[(size_t)i * 2]     = mu;
        st[(size_t)i * 2 + 1] = rsqrtf(var + EPSF);
    }
}

// ------------------------------------------------- GEMM1: xz = LN(x) @ Wi^T
// M=32768, N=1024, K=256. Tile 128x64, KT=16. 256 thr, 8x4 acc.
__global__ __launch_bounds__(256) void k_gemm1(
    const float* __restrict__ x, const float* __restrict__ st,
    const float* __restrict__ gam, const float* __restrict__ bet,
    const float* __restrict__ W, float* __restrict__ xz) {
    __shared__ float As[16][128];
    __shared__ float Bs[16][64];
    int tid = threadIdx.x;
    int tileN = blockIdx.x & 15, tileM = blockIdx.x >> 4;
    int i0 = tileM * 128, n0 = tileN * 64;
    int tx = tid & 15, ty = tid >> 4;
    float acc[8][4];
    #pragma unroll
    for (int r = 0; r < 8; r++)
        #pragma unroll
        for (int c = 0; c < 4; c++) acc[r][c] = 0.0f;

    for (int k0 = 0; k0 < 256; k0 += 16) {
        __syncthreads();
        #pragma unroll
        for (int j = 0; j < 2; j++) {               // A tile: 128 rows x 16 k (LN applied)
            int q = tid * 2 + j;
            int ar = q >> 2, af = q & 3;
            int gi = i0 + ar;
            float4 v = *(const float4*)(x + (size_t)gi * DM + k0 + af * 4);
            float mu = st[(size_t)gi * 2], rs = st[(size_t)gi * 2 + 1];
            int kb = k0 + af * 4;
            As[af * 4 + 0][ar] = (v.x - mu) * rs * gam[kb + 0] + bet[kb + 0];
            As[af * 4 + 1][ar] = (v.y - mu) * rs * gam[kb + 1] + bet[kb + 1];
            As[af * 4 + 2][ar] = (v.z - mu) * rs * gam[kb + 2] + bet[kb + 2];
            As[af * 4 + 3][ar] = (v.w - mu) * rs * gam[kb + 3] + bet[kb + 3];
        }
        {                                           // B tile: 64 rows(n) x 16 k
            int br = tid >> 2, bf = tid & 3;
            float4 v = *(const float4*)(W + (size_t)(n0 + br) * 256 + k0 + bf * 4);
            Bs[bf * 4 + 0][br] = v.x;
            Bs[bf * 4 + 1][br] = v.y;
            Bs[bf * 4 + 2][br] = v.z;
            Bs[bf * 4 + 3][br] = v.w;
        }
        __syncthreads();
        #pragma unroll
        for (int kk = 0; kk < 16; kk++) {
            float4 bv = *(const float4*)&Bs[kk][tx * 4];
            float4 a0 = *(const float4*)&As[kk][ty * 8];
            float4 a1 = *(const float4*)&As[kk][ty * 8 + 4];
            float av[8] = {a0.x, a0.y, a0.z, a0.w, a1.x, a1.y, a1.z, a1.w};
            float bw[4] = {bv.x, bv.y, bv.z, bv.w};
            #pragma unroll
            for (int r = 0; r < 8; r++)
                #pragma unroll
                for (int c = 0; c < 4; c++)
                    acc[r][c] = fmaf(av[r], bw[c], acc[r][c]);
        }
    }
    #pragma unroll
    for (int r = 0; r < 8; r++) {
        float4 o = make_float4(acc[r][0], acc[r][1], acc[r][2], acc[r][3]);
        *(float4*)(xz + (size_t)(i0 + ty * 8 + r) * 1024 + n0 + tx * 4) = o;
    }
}

// -------------------------------------------- depthwise causal conv + SiLU
__global__ void k_conv(const float* __restrict__ xz, const float* __restrict__ cw,
                       const float* __restrict__ cb, float* __restrict__ xc) {
    int g = blockIdx.x * 256 + threadIdx.x;     // NTOK*128 threads
    int i = g >> 7, dq = g & 127;
    int t = i & (SEQL - 1);
    int d = dq * 4;
    float4 acc = *(const float4*)(cb + d);
    #pragma unroll
    for (int k = 0; k < 4; k++) {
        int tt = t + k - 3;
        if (tt >= 0) {
            float4 v = *(const float4*)(xz + (size_t)(i + k - 3) * 1024 + d);
            acc.x = fmaf(v.x, cw[(d + 0) * 4 + k], acc.x);
            acc.y = fmaf(v.y, cw[(d + 1) * 4 + k], acc.y);
            acc.z = fmaf(v.z, cw[(d + 2) * 4 + k], acc.z);
            acc.w = fmaf(v.w, cw[(d + 3) * 4 + k], acc.w);
        }
    }
    acc.x = siluf_(acc.x); acc.y = siluf_(acc.y);
    acc.z = siluf_(acc.z); acc.w = siluf_(acc.w);
    *(float4*)(xc + (size_t)i * DI + d) = acc;
}

// ---------------------------------------- xproj: ssm = xc @ Wx^T (N=33)
__global__ __launch_bounds__(256) void k_xproj(
    const float* __restrict__ xc, const float* __restrict__ W,
    float* __restrict__ Bm, float* __restrict__ Cm, float* __restrict__ dtr) {
    __shared__ float Wl[33 * 261];
    int tid = threadIdx.x, lane = tid & 63, wid = tid >> 6;
    int tok0 = blockIdx.x * 32;                 // 32 tokens/block, 8 per wave
    float acc[8];
    #pragma unroll
    for (int j = 0; j < 8; j++) acc[j] = 0.0f;

    for (int kh = 0; kh < 2; kh++) {
        __syncthreads();
        for (int idx = tid; idx < 33 * 256; idx += 256) {
            int r = idx >> 8, c = idx & 255;
            Wl[r * 261 + c] = W[(size_t)r * DI + kh * 256 + c];
        }
        __syncthreads();
        if (lane < 33) {
            for (int j = 0; j < 8; j++) {
                int i = tok0 + wid * 8 + j;
                const float* xr = xc + (size_t)i * DI + kh * 256;
                const float* wr = &Wl[lane * 261];
                float a = acc[j];
                #pragma unroll 4
                for (int k = 0; k < 256; k += 4) {
                    float4 xv = *(const float4*)(xr + k);
                    a = fmaf(xv.x, wr[k + 0], a);
                    a = fmaf(xv.y, wr[k + 1], a);
                    a = fmaf(xv.z, wr[k + 2], a);
                    a = fmaf(xv.w, wr[k + 3], a);
                }
                acc[j] = a;
            }
        }
    }
    if (lane < 33) {
        for (int j = 0; j < 8; j++) {
            int i = tok0 + wid * 8 + j;
            if (lane < 16)      Bm[(size_t)i * DS + lane] = acc[j];
            else if (lane < 32) Cm[(size_t)i * DS + lane - 16] = acc[j];
            else                dtr[i] = acc[j];
        }
    }
}

// ------------------------------------------------ scan phase 1: local scans
__global__ __launch_bounds__(256) void k_scan1(
    const float* __restrict__ xc, const float* __restrict__ Bm,
    const float* __restrict__ Cm, const float* __restrict__ dtr,
    const float* __restrict__ dw, const float* __restrict__ db,
    float* __restrict__ yp /* xz base */, float* __restrict__ hend,
    float* __restrict__ dtc) {
    int g = blockIdx.x * 256 + threadIdx.x;     // BATCH*DI*NCH
    int d = g & 511, c = (g >> 9) & (NCH - 1), b = g >> 14;
    float h[16];
    #pragma unroll
    for (int s = 0; s < 16; s++) h[s] = 0.0f;
    float dwd = dw[d], dbd = db[d];
    float dts = 0.0f;
    int t0 = c * TC;
    for (int t = t0; t < t0 + TC; t++) {
        int i = (b << 12) + t;
        float dt = softplusf_(fmaf(dtr[i], dwd, dbd));
        dts += dt;
        float p = __expf(-dt);
        float dtx = dt * xc[(size_t)i * DI + d];
        float Bv[16], Cv[16];
        *(float4*)(Bv + 0)  = *(const float4*)(Bm + (size_t)i * DS + 0);
        *(float4*)(Bv + 4)  = *(const float4*)(Bm + (size_t)i * DS + 4);
        *(float4*)(Bv + 8)  = *(const float4*)(Bm + (size_t)i * DS + 8);
        *(float4*)(Bv + 12) = *(const float4*)(Bm + (size_t)i * DS + 12);
        *(float4*)(Cv + 0)  = *(const float4*)(Cm + (size_t)i * DS + 0);
        *(float4*)(Cv + 4)  = *(const float4*)(Cm + (size_t)i * DS + 4);
        *(float4*)(Cv + 8)  = *(const float4*)(Cm + (size_t)i * DS + 8);
        *(float4*)(Cv + 12) = *(const float4*)(Cm + (size_t)i * DS + 12);
        float y = 0.0f, pb = 1.0f;
        #pragma unroll
        for (int s = 0; s < 16; s++) {
            pb *= p;                              // pb = exp(-(s+1)*dt) = A_bar
            h[s] = fmaf(pb, h[s], dtx * Bv[s]);
            y = fmaf(h[s], Cv[s], y);
        }
        yp[(size_t)i * 1024 + d] = y;             // partial y into xp slot
    }
    size_t hb = ((size_t)(b * DI + d) * NCH + c) * DS;
    #pragma unroll
    for (int s = 0; s < 16; s += 4)
        *(float4*)(hend + hb + s) = make_float4(h[s], h[s + 1], h[s + 2], h[s + 3]);
    dtc[(size_t)(b * DI + d) * NCH + c] = dts;
}

// ------------------------------------- scan phase 2: chunk-boundary states
__global__ void k_scan2(float* __restrict__ hend, const float* __restrict__ dtc) {
    int g = blockIdx.x * 256 + threadIdx.x;     // BATCH*DI
    int d = g & 511, b = g >> 9;
    float hin[16];
    #pragma unroll
    for (int s = 0; s < 16; s++) hin[s] = 0.0f;
    size_t base = (size_t)(b * DI + d) * NCH;
    for (int c = 0; c < NCH; c++) {
        size_t hb = (base + c) * DS;
        float tmp[16];
        #pragma unroll
        for (int s = 0; s < 16; s += 4) *(float4*)(tmp + s) = *(const float4*)(hend + hb + s);
        #pragma unroll
        for (int s = 0; s < 16; s += 4)
            *(float4*)(hend + hb + s) = make_float4(hin[s], hin[s+1], hin[s+2], hin[s+3]);
        float p = __expf(-dtc[base + c]);
        float pb = 1.0f;
        #pragma unroll
        for (int s = 0; s < 16; s++) {
            pb *= p;
            hin[s] = fmaf(pb, hin[s], tmp[s]);
        }
    }
}

// ----------------------- scan phase 3: correction + gate, write gated y
__global__ __launch_bounds__(256) void k_scan3(
    const float* __restrict__ Cm, const float* __restrict__ dtr,
    const float* __restrict__ dw, const float* __restrict__ db,
    const float* __restrict__ hend, float* __restrict__ xz) {
    int g = blockIdx.x * 256 + threadIdx.x;     // BATCH*DI*NCH
    int d = g & 511, c = (g >> 9) & (NCH - 1), b = g >> 14;
    float hd[16];
    size_t hb = ((size_t)(b * DI + d) * NCH + c) * DS;
    #pragma unroll
    for (int s = 0; s < 16; s += 4) *(float4*)(hd + s) = *(const float4*)(hend + hb + s);
    float dwd = dw[d], dbd = db[d];
    int t0 = c * TC;
    for (int t = t0; t < t0 + TC; t++) {
        int i = (b << 12) + t;
        float dt = softplusf_(fmaf(dtr[i], dwd, dbd));
        float p = __expf(-dt);
        float Cv[16];
        *(float4*)(Cv + 0)  = *(const float4*)(Cm + (size_t)i * DS + 0);
        *(float4*)(Cv + 4)  = *(const float4*)(Cm + (size_t)i * DS + 4);
        *(float4*)(Cv + 8)  = *(const float4*)(Cm + (size_t)i * DS + 8);
        *(float4*)(Cv + 12) = *(const float4*)(Cm + (size_t)i * DS + 12);
        float corr = 0.0f, pb = 1.0f;
        #pragma unroll
        for (int s = 0; s < 16; s++) {
            pb *= p;
            hd[s] *= pb;                          // decay incoming state through step t
            corr = fmaf(hd[s], Cv[s], corr);
        }
        float y = xz[(size_t)i * 1024 + d] + corr;
        float z = xz[(size_t)i * 1024 + DI + d];
        xz[(size_t)i * 1024 + d] = y * siluf_(z);
    }
}

// --------------------------------- outproj: x += yg @ Wo^T  (residual add)
// M=32768, N=256, K=512. A stride 1024 (yg in xz). Tile 128x64, KT=16.
__global__ __launch_bounds__(256) void k_outproj(
    const float* __restrict__ yg, const float* __restrict__ W,
    float* __restrict__ x) {
    __shared__ float As[16][128];
    __shared__ float Bs[16][64];
    int tid = threadIdx.x;
    int tileN = blockIdx.x & 3, tileM = blockIdx.x >> 2;
    int i0 = tileM * 128, n0 = tileN * 64;
    int tx = tid & 15, ty = tid >> 4;
    float acc[8][4];
    #pragma unroll
    for (int r = 0; r < 8; r++)
        #pragma unroll
        for (int c = 0; c < 4; c++) acc[r][c] = 0.0f;

    for (int k0 = 0; k0 < 512; k0 += 16) {
        __syncthreads();
        #pragma unroll
        for (int j = 0; j < 2; j++) {
            int q = tid * 2 + j;
            int ar = q >> 2, af = q & 3;
            float4 v = *(const float4*)(yg + (size_t)(i0 + ar) * 1024 + k0 + af * 4);
            As[af * 4 + 0][ar] = v.x;
            As[af * 4 + 1][ar] = v.y;
            As[af * 4 + 2][ar] = v.z;
            As[af * 4 + 3][ar] = v.w;
        }
        {
            int br = tid >> 2, bf = tid & 3;
            float4 v = *(const float4*)(W + (size_t)(n0 + br) * DI + k0 + bf * 4);
            Bs[bf * 4 + 0][br] = v.x;
            Bs[bf * 4 + 1][br] = v.y;
            Bs[bf * 4 + 2][br] = v.z;
            Bs[bf * 4 + 3][br] = v.w;
        }
        __syncthreads();
        #pragma unroll
        for (int kk = 0; kk < 16; kk++) {
            float4 bv = *(const float4*)&Bs[kk][tx * 4];
            float4 a0 = *(const float4*)&As[kk][ty * 8];
            float4 a1 = *(const float4*)&As[kk][ty * 8 + 4];
            float av[8] = {a0.x, a0.y, a0.z, a0.w, a1.x, a1.y, a1.z, a1.w};
            float bw[4] = {bv.x, bv.y, bv.z, bv.w};
            #pragma unroll
            for (int r = 0; r < 8; r++)
                #pragma unroll
                for (int c = 0; c < 4; c++)
                    acc[r][c] = fmaf(av[r], bw[c], acc[r][c]);
        }
    }
    #pragma unroll
    for (int r = 0; r < 8; r++) {
        float4* px = (float4*)(x + (size_t)(i0 + ty * 8 + r) * DM + n0 + tx * 4);
        float4 o = *px;
        o.x += acc[r][0]; o.y += acc[r][1]; o.z += acc[r][2]; o.w += acc[r][3];
        *px = o;
    }
}

// -------------------------------------------- final LN + output projection
__global__ void k_final(const float* __restrict__ x, const float* __restrict__ gam,
                        const float* __restrict__ bet, const float* __restrict__ w,
                        const float* __restrict__ bias, float* __restrict__ out) {
    int lane = threadIdx.x & 63, wid = threadIdx.x >> 6;
    int i = blockIdx.x * 4 + wid;
    float4 v = *(const float4*)(x + (size_t)i * DM + lane * 4);
    float s = v.x + v.y + v.z + v.w;
    float q = v.x * v.x + v.y * v.y + v.z * v.z + v.w * v.w;
    #pragma unroll
    for (int m = 32; m; m >>= 1) { s += __shfl_xor(s, m, 64); q += __shfl_xor(q, m, 64); }
    float mu = s * (1.0f / DM);
    float rs = rsqrtf(q * (1.0f / DM) - mu * mu + EPSF);
    float4 gg = *(const float4*)(gam + lane * 4);
    float4 bb = *(const float4*)(bet + lane * 4);
    float xn[4] = {(v.x - mu) * rs * gg.x + bb.x, (v.y - mu) * rs * gg.y + bb.y,
                   (v.z - mu) * rs * gg.z + bb.z, (v.w - mu) * rs * gg.w + bb.w};
    float4 w0 = *(const float4*)(w + lane * 4);
    float4 w1 = *(const float4*)(w + DM + lane * 4);
    float p0 = xn[0] * w0.x + xn[1] * w0.y + xn[2] * w0.z + xn[3] * w0.w;
    float p1 = xn[0] * w1.x + xn[1] * w1.y + xn[2] * w1.z + xn[3] * w1.w;
    #pragma unroll
    for (int m = 32; m; m >>= 1) { p0 += __shfl_xor(p0, m, 64); p1 += __shfl_xor(p1, m, 64); }
    if (lane == 0) {
        out[(size_t)i * 2]     = p0 + bias[0];
        out[(size_t)i * 2 + 1] = p1 + bias[1];
    }
}

// ---------------------------------------------------------------------------
extern "C" void kernel_launch(void* const* d_in, const int* in_sizes, int n_in,
                              void* d_out, int out_size, void* d_ws, size_t ws_size,
                              hipStream_t stream) {
    const float* z_seq     = (const float*)d_in[0];
    const float* ip_w      = (const float*)d_in[1];
    const float* ip_b      = (const float*)d_in[2];
    const float* norm_g    = (const float*)d_in[3];
    const float* norm_b    = (const float*)d_in[4];
    const float* inproj_w  = (const float*)d_in[5];
    const float* conv_w    = (const float*)d_in[6];
    const float* conv_b    = (const float*)d_in[7];
    const float* xproj_w   = (const float*)d_in[8];
    const float* dt_w      = (const float*)d_in[9];
    const float* dt_b      = (const float*)d_in[10];
    const float* outproj_w = (const float*)d_in[11];
    const float* onorm_g   = (const float*)d_in[12];
    const float* onorm_b   = (const float*)d_in[13];
    const float* op_w      = (const float*)d_in[14];
    const float* op_b      = (const float*)d_in[15];

    float* ws   = (float*)d_ws;
    float* x    = ws + OFF_X;
    float* xz   = ws + OFF_XZ;
    float* xc   = ws + OFF_XC;
    float* Bmb  = ws + OFF_B;
    float* Cmb  = ws + OFF_C;
    float* dtrb = ws + OFF_DTR;
    float* st   = ws + OFF_ST;
    float* hend = ws + OFF_HE;
    float* dtc  = ws + OFF_DTC;

    k_inproj<<<NTOK * DM / 256, 256, 0, stream>>>(z_seq, ip_w, ip_b, x);

    for (int l = 0; l < 2; l++) {
        k_stats<<<NTOK / 4, 256, 0, stream>>>(x, st);
        k_gemm1<<<(NTOK / 128) * (1024 / 64), 256, 0, stream>>>(
            x, st, norm_g + l * DM, norm_b + l * DM, inproj_w + (size_t)l * 2 * DI * DM, xz);
        k_conv<<<NTOK * (DI / 4) / 256, 256, 0, stream>>>(
            xz, conv_w + (size_t)l * DI * 4, conv_b + (size_t)l * DI, xc);
        k_xproj<<<NTOK / 32, 256, 0, stream>>>(
            xc, xproj_w + (size_t)l * 33 * DI, Bmb, Cmb, dtrb);
        k_scan1<<<BATCH * DI * NCH / 256, 256, 0, stream>>>(
            xc, Bmb, Cmb, dtrb, dt_w + l * DI, dt_b + l * DI, xz, hend, dtc);
        k_scan2<<<BATCH * DI / 256, 256, 0, stream>>>(hend, dtc);
        k_scan3<<<BATCH * DI * NCH / 256, 256, 0, stream>>>(
            Cmb, dtrb, dt_w + l * DI, dt_b + l * DI, hend, xz);
        k_outproj<<<(NTOK / 128) * (DM / 64), 256, 0, stream>>>(
            xz, outproj_w + (size_t)l * DM * DI, x);
    }
    k_final<<<NTOK / 4, 256, 0, stream>>>(x, onorm_g, onorm_b, op_w, op_b, (float*)d_out);
}

// Round 3
// 1210.852 us; speedup vs baseline: 1.6002x; 1.6002x over previous
//
#include <hip/hip_runtime.h>
#include <cstddef>
#include <cstdint>

#define DEV __device__ __forceinline__

namespace {
constexpr int BATCH = 8;
constexpr int SEQL  = 4096;
constexpr int DM    = 256;   // d_model
constexpr int DS    = 16;    // d_state
constexpr int DI    = 512;   // d_inner
constexpr int NTOK  = BATCH * SEQL;   // 32768
constexpr int TC    = 64;             // scan chunk length
constexpr int NCH   = SEQL / TC;      // 64 chunks per sequence
constexpr float EPSF = 1e-5f;

// workspace offsets (bytes)
constexpr size_t OFF_X   = 0;                                  // fp32 NTOK*DM
constexpr size_t OFF_Z   = OFF_X   + (size_t)NTOK * DM  * 4;   // fp32 NTOK*DI
constexpr size_t OFF_XC  = OFF_Z   + (size_t)NTOK * DI  * 4;   // fp32 NTOK*DI (xc, then partial y in-place)
constexpr size_t OFF_XPB = OFF_XC  + (size_t)NTOK * DI  * 4;   // bf16 NTOK*DI (xp, then gated-y in-place)
constexpr size_t OFF_XLN = OFF_XPB + (size_t)NTOK * DI  * 2;   // bf16 NTOK*DM
constexpr size_t OFF_B   = OFF_XLN + (size_t)NTOK * DM  * 2;   // fp32 NTOK*DS
constexpr size_t OFF_C   = OFF_B   + (size_t)NTOK * DS  * 4;   // fp32 NTOK*DS
constexpr size_t OFF_DTR = OFF_C   + (size_t)NTOK * DS  * 4;   // fp32 NTOK
constexpr size_t OFF_HE  = OFF_DTR + (size_t)NTOK * 4;         // fp32 BATCH*DI*NCH*DS
constexpr size_t OFF_DTC = OFF_HE  + (size_t)BATCH * DI * NCH * DS * 4; // fp32 BATCH*DI*NCH
constexpr size_t OFF_WB  = OFF_DTC + (size_t)BATCH * DI * NCH * 4;      // bf16 weights
// WB layout: WbI (2*1024*256 bf16) | WbO (2*256*512 bf16)
constexpr size_t WBI_EL  = 2 * 2 * DI * DM;   // 524288
constexpr size_t WBO_EL  = 2 * DM * DI;       // 262144
} // namespace

typedef __attribute__((ext_vector_type(8))) short short8;
typedef __attribute__((ext_vector_type(4))) float f32x4;

DEV float sigmoidf_(float v) { return 1.0f / (1.0f + __expf(-v)); }
DEV float siluf_(float v)    { return v * sigmoidf_(v); }
DEV float softplusf_(float v) {  // fast: no log1pf libcall
    return fmaxf(v, 0.0f) + __logf(1.0f + __expf(-fabsf(v)));
}
DEV float b2f(unsigned short u) {
    union { unsigned int i; float f; } c; c.i = ((unsigned int)u) << 16; return c.f;
}
DEV unsigned short f2b(float f) {  // round-to-nearest-even
    union { float f; unsigned int i; } c; c.f = f;
    unsigned int lsb = (c.i >> 16) & 1u;
    c.i += 0x7fffu + lsb;
    return (unsigned short)(c.i >> 16);
}
DEV void pows16(float p, float* pb) {  // pb[s] = p^(s+1), dep-depth ~4
    float p2 = p * p, p4 = p2 * p2, p8 = p4 * p4;
    pb[0] = p;        pb[1] = p2;       pb[2] = p2 * p;      pb[3] = p4;
    pb[4] = p4 * p;   pb[5] = p4 * p2;  pb[6] = p4 * p2 * p; pb[7] = p8;
    pb[8] = p8 * p;   pb[9] = p8 * p2;  pb[10] = p8 * p2 * p; pb[11] = p8 * p4;
    pb[12] = p8 * p4 * p; pb[13] = p8 * p4 * p2; pb[14] = p8 * p4 * p2 * p; pb[15] = p8 * p8;
}
DEV void gload_lds16(const unsigned short* g, unsigned short* l) {
    __builtin_amdgcn_global_load_lds(
        (__attribute__((address_space(1))) void*)(g),
        (__attribute__((address_space(3))) void*)(l), 16, 0, 0);
}

// ------------------------------------------------------------- f32 -> bf16
__global__ void k_cvt(const float* __restrict__ src, unsigned short* __restrict__ dst, int n) {
    int g = (blockIdx.x * 256 + threadIdx.x) * 4;
    if (g >= n) return;
    float4 v = *(const float4*)(src + g);
    ushort4 o;
    o.x = f2b(v.x); o.y = f2b(v.y); o.z = f2b(v.z); o.w = f2b(v.w);
    *(ushort4*)(dst + g) = o;
}

// ---------------------------------------------------------------- input proj
__global__ void k_inproj(const float* __restrict__ z, const float* __restrict__ w,
                         const float* __restrict__ bias, float* __restrict__ x) {
    int g = blockIdx.x * 256 + threadIdx.x;     // NTOK*DM threads
    int i = g >> 8, m = g & 255;
    float4 zv = *(const float4*)(z + (size_t)i * 4);
    float4 wv = *(const float4*)(w + (size_t)m * 4);
    float r = bias[m];
    r = fmaf(zv.x, wv.x, r);
    r = fmaf(zv.y, wv.y, r);
    r = fmaf(zv.z, wv.z, r);
    r = fmaf(zv.w, wv.w, r);
    x[g] = r;
}

// -------------------------------------------- fused row-LN -> bf16 (per wave)
__global__ void k_lnrow(const float* __restrict__ x, const float* __restrict__ gam,
                        const float* __restrict__ bet, unsigned short* __restrict__ xln) {
    int lane = threadIdx.x & 63, wid = threadIdx.x >> 6;
    int i = blockIdx.x * 4 + wid;
    float4 v = *(const float4*)(x + (size_t)i * DM + lane * 4);
    float s = v.x + v.y + v.z + v.w;
    float q = v.x * v.x + v.y * v.y + v.z * v.z + v.w * v.w;
    #pragma unroll
    for (int m = 32; m; m >>= 1) { s += __shfl_xor(s, m, 64); q += __shfl_xor(q, m, 64); }
    float mu = s * (1.0f / DM);
    float rs = rsqrtf(q * (1.0f / DM) - mu * mu + EPSF);
    float4 g4 = *(const float4*)(gam + lane * 4);
    float4 b4 = *(const float4*)(bet + lane * 4);
    ushort4 o;
    o.x = f2b((v.x - mu) * rs * g4.x + b4.x);
    o.y = f2b((v.y - mu) * rs * g4.y + b4.y);
    o.z = f2b((v.z - mu) * rs * g4.z + b4.z);
    o.w = f2b((v.w - mu) * rs * g4.w + b4.w);
    *(ushort4*)(xln + (size_t)i * DM + lane * 4) = o;
}

// ------------------------------------- GEMM1 (MFMA): xz = xln @ WbI^T
// M=32768 N=1024 K=256, bf16 in, tile 128x128, BK=32, 4 waves.
// N-tiles 0..3 -> xpb (bf16), 4..7 -> Z (fp32)
__global__ __launch_bounds__(256) void k_gemm1(
    const unsigned short* __restrict__ A, const unsigned short* __restrict__ W,
    unsigned short* __restrict__ xpb, float* __restrict__ Z) {
    __shared__ unsigned short As[128 * 32];
    __shared__ unsigned short Bs[128 * 32];
    int tid = threadIdx.x, lane = tid & 63, wid = tid >> 6;
    int tileN = blockIdx.x & 7, tileM = blockIdx.x >> 3;
    int i0 = tileM * 128, n0 = tileN * 128;
    f32x4 acc[4][4];
    #pragma unroll
    for (int mi = 0; mi < 4; mi++)
        #pragma unroll
        for (int ni = 0; ni < 4; ni++) acc[mi][ni] = (f32x4){0.f, 0.f, 0.f, 0.f};

    int srow = (wid << 5) + (lane >> 2);   // staging row (issue 0)
    int sblk = lane & 3;
    const unsigned short* ga = A + (size_t)(i0 + srow) * 256 + sblk * 8;
    const unsigned short* gb = W + (size_t)(n0 + srow) * 256 + sblk * 8;
    unsigned short* la = As + (wid << 5) * 32;   // wave-uniform LDS base
    unsigned short* lb = Bs + (wid << 5) * 32;
    int ar = lane & 15, ab = lane >> 4;
    const short8* pa = (const short8*)(As + ((wid >> 1) * 64 + ar) * 32 + ab * 8);
    const short8* pb = (const short8*)(Bs + ((wid & 1) * 64 + ar) * 32 + ab * 8);

    for (int k0 = 0; k0 < 256; k0 += 32) {
        gload_lds16(ga + k0,            la);
        gload_lds16(ga + k0 + 16 * 256, la + 16 * 32);
        gload_lds16(gb + k0,            lb);
        gload_lds16(gb + k0 + 16 * 256, lb + 16 * 32);
        __syncthreads();
        short8 a[4], b[4];
        #pragma unroll
        for (int mi = 0; mi < 4; mi++) a[mi] = pa[mi * 64];
        #pragma unroll
        for (int ni = 0; ni < 4; ni++) b[ni] = pb[ni * 64];
        #pragma unroll
        for (int mi = 0; mi < 4; mi++)
            #pragma unroll
            for (int ni = 0; ni < 4; ni++)
                acc[mi][ni] = __builtin_amdgcn_mfma_f32_16x16x32_bf16(a[mi], b[ni], acc[mi][ni], 0, 0, 0);
        __syncthreads();
    }
    int wr = wid >> 1, wc = wid & 1;
    int rbase = i0 + wr * 64 + (lane >> 4) * 4;
    int cbase = n0 + wc * 64 + (lane & 15);
    if (n0 < 512) {
        #pragma unroll
        for (int mi = 0; mi < 4; mi++)
            #pragma unroll
            for (int ni = 0; ni < 4; ni++)
                #pragma unroll
                for (int j = 0; j < 4; j++)
                    xpb[(size_t)(rbase + mi * 16 + j) * 512 + cbase + ni * 16] = f2b(acc[mi][ni][j]);
    } else {
        #pragma unroll
        for (int mi = 0; mi < 4; mi++)
            #pragma unroll
            for (int ni = 0; ni < 4; ni++)
                #pragma unroll
                for (int j = 0; j < 4; j++)
                    Z[(size_t)(rbase + mi * 16 + j) * 512 + cbase + ni * 16 - 512] = acc[mi][ni][j];
    }
}

// -------------------------------------------- depthwise causal conv + SiLU
__global__ void k_conv(const unsigned short* __restrict__ xpb, const float* __restrict__ cw,
                       const float* __restrict__ cb, float* __restrict__ xc) {
    int g = blockIdx.x * 256 + threadIdx.x;     // NTOK*128 threads
    int i = g >> 7, dq = g & 127;
    int t = i & (SEQL - 1);
    int d = dq * 4;
    float4 acc = *(const float4*)(cb + d);
    #pragma unroll
    for (int k = 0; k < 4; k++) {
        int tt = t + k - 3;
        if (tt >= 0) {
            ushort4 v = *(const ushort4*)(xpb + (size_t)(i + k - 3) * 512 + d);
            acc.x = fmaf(b2f(v.x), cw[(d + 0) * 4 + k], acc.x);
            acc.y = fmaf(b2f(v.y), cw[(d + 1) * 4 + k], acc.y);
            acc.z = fmaf(b2f(v.z), cw[(d + 2) * 4 + k], acc.z);
            acc.w = fmaf(b2f(v.w), cw[(d + 3) * 4 + k], acc.w);
        }
    }
    acc.x = siluf_(acc.x); acc.y = siluf_(acc.y);
    acc.z = siluf_(acc.z); acc.w = siluf_(acc.w);
    *(float4*)(xc + (size_t)i * DI + d) = acc;
}

// ---------------------------------------- xproj: ssm = xc @ Wx^T (N=33)
__global__ __launch_bounds__(256) void k_xproj(
    const float* __restrict__ xc, const float* __restrict__ W,
    float* __restrict__ Bm, float* __restrict__ Cm, float* __restrict__ dtr) {
    __shared__ float Wl[33 * 261];
    int tid = threadIdx.x, lane = tid & 63, wid = tid >> 6;
    int tok0 = blockIdx.x * 32;                 // 32 tokens/block, 8 per wave
    float acc[8];
    #pragma unroll
    for (int j = 0; j < 8; j++) acc[j] = 0.0f;

    for (int kh = 0; kh < 2; kh++) {
        __syncthreads();
        for (int idx = tid; idx < 33 * 256; idx += 256) {
            int r = idx >> 8, c = idx & 255;
            Wl[r * 261 + c] = W[(size_t)r * DI + kh * 256 + c];
        }
        __syncthreads();
        if (lane < 33) {
            for (int j = 0; j < 8; j++) {
                int i = tok0 + wid * 8 + j;
                const float* xr = xc + (size_t)i * DI + kh * 256;
                const float* wr = &Wl[lane * 261];
                float a = acc[j];
                #pragma unroll 4
                for (int k = 0; k < 256; k += 4) {
                    float4 xv = *(const float4*)(xr + k);
                    a = fmaf(xv.x, wr[k + 0], a);
                    a = fmaf(xv.y, wr[k + 1], a);
                    a = fmaf(xv.z, wr[k + 2], a);
                    a = fmaf(xv.w, wr[k + 3], a);
                }
                acc[j] = a;
            }
        }
    }
    if (lane < 33) {
        for (int j = 0; j < 8; j++) {
            int i = tok0 + wid * 8 + j;
            if (lane < 16)      Bm[(size_t)i * DS + lane] = acc[j];
            else if (lane < 32) Cm[(size_t)i * DS + lane - 16] = acc[j];
            else                dtr[i] = acc[j];
        }
    }
}

// ------------------------------------------------ scan phase 1: local scans
// reads xc, writes partial y IN-PLACE over xc
__global__ __launch_bounds__(256) void k_scan1(
    float* __restrict__ xc, const float* __restrict__ Bm,
    const float* __restrict__ Cm, const float* __restrict__ dtr,
    const float* __restrict__ dw, const float* __restrict__ db,
    float* __restrict__ hend, float* __restrict__ dtc) {
    int g = blockIdx.x * 256 + threadIdx.x;     // BATCH*DI*NCH = 262144
    int d = g & 511, c = (g >> 9) & (NCH - 1), b = g >> 15;
    float h[16];
    #pragma unroll
    for (int s = 0; s < 16; s++) h[s] = 0.0f;
    float dwd = dw[d], dbd = db[d];
    float dts = 0.0f;
    int t0 = c * TC;
    for (int t = t0; t < t0 + TC; t++) {
        int i = (b << 12) + t;
        float dt = softplusf_(fmaf(dtr[i], dwd, dbd));
        dts += dt;
        float p = __expf(-dt);
        float pb[16];
        pows16(p, pb);
        float dtx = dt * xc[(size_t)i * DI + d];
        float Bv[16], Cv[16];
        *(float4*)(Bv + 0)  = *(const float4*)(Bm + (size_t)i * DS + 0);
        *(float4*)(Bv + 4)  = *(const float4*)(Bm + (size_t)i * DS + 4);
        *(float4*)(Bv + 8)  = *(const float4*)(Bm + (size_t)i * DS + 8);
        *(float4*)(Bv + 12) = *(const float4*)(Bm + (size_t)i * DS + 12);
        *(float4*)(Cv + 0)  = *(const float4*)(Cm + (size_t)i * DS + 0);
        *(float4*)(Cv + 4)  = *(const float4*)(Cm + (size_t)i * DS + 4);
        *(float4*)(Cv + 8)  = *(const float4*)(Cm + (size_t)i * DS + 8);
        *(float4*)(Cv + 12) = *(const float4*)(Cm + (size_t)i * DS + 12);
        float y = 0.0f;
        #pragma unroll
        for (int s = 0; s < 16; s++) {
            h[s] = fmaf(pb[s], h[s], dtx * Bv[s]);
            y = fmaf(h[s], Cv[s], y);
        }
        xc[(size_t)i * DI + d] = y;            // overwrite with partial y
    }
    size_t hb = ((size_t)(b * DI + d) * NCH + c) * DS;
    #pragma unroll
    for (int s = 0; s < 16; s += 4)
        *(float4*)(hend + hb + s) = make_float4(h[s], h[s + 1], h[s + 2], h[s + 3]);
    dtc[(size_t)(b * DI + d) * NCH + c] = dts;
}

// ------------------------------------- scan phase 2: chunk-boundary states
__global__ void k_scan2(float* __restrict__ hend, const float* __restrict__ dtc) {
    int g = blockIdx.x * 256 + threadIdx.x;     // BATCH*DI = 4096
    int d = g & 511, b = g >> 9;
    float hin[16];
    #pragma unroll
    for (int s = 0; s < 16; s++) hin[s] = 0.0f;
    size_t base = (size_t)(b * DI + d) * NCH;
    for (int c = 0; c < NCH; c++) {
        size_t hb = (base + c) * DS;
        float tmp[16];
        #pragma unroll
        for (int s = 0; s < 16; s += 4) *(float4*)(tmp + s) = *(const float4*)(hend + hb + s);
        #pragma unroll
        for (int s = 0; s < 16; s += 4)
            *(float4*)(hend + hb + s) = make_float4(hin[s], hin[s+1], hin[s+2], hin[s+3]);
        float p = __expf(-dtc[base + c]);
        float pb[16];
        pows16(p, pb);
        #pragma unroll
        for (int s = 0; s < 16; s++) hin[s] = fmaf(pb[s], hin[s], tmp[s]);
    }
}

// ----------------- scan phase 3: correction + gate, write gated y (bf16)
__global__ __launch_bounds__(256) void k_scan3(
    const float* __restrict__ Cm, const float* __restrict__ dtr,
    const float* __restrict__ dw, const float* __restrict__ db,
    const float* __restrict__ hend, const float* __restrict__ yp /* xc */,
    const float* __restrict__ Z, unsigned short* __restrict__ ygb /* xpb */) {
    int g = blockIdx.x * 256 + threadIdx.x;     // BATCH*DI*NCH
    int d = g & 511, c = (g >> 9) & (NCH - 1), b = g >> 15;
    float hd[16];
    size_t hb = ((size_t)(b * DI + d) * NCH + c) * DS;
    #pragma unroll
    for (int s = 0; s < 16; s += 4) *(float4*)(hd + s) = *(const float4*)(hend + hb + s);
    float dwd = dw[d], dbd = db[d];
    int t0 = c * TC;
    for (int t = t0; t < t0 + TC; t++) {
        int i = (b << 12) + t;
        float dt = softplusf_(fmaf(dtr[i], dwd, dbd));
        float p = __expf(-dt);
        float pb[16];
        pows16(p, pb);
        float Cv[16];
        *(float4*)(Cv + 0)  = *(const float4*)(Cm + (size_t)i * DS + 0);
        *(float4*)(Cv + 4)  = *(const float4*)(Cm + (size_t)i * DS + 4);
        *(float4*)(Cv + 8)  = *(const float4*)(Cm + (size_t)i * DS + 8);
        *(float4*)(Cv + 12) = *(const float4*)(Cm + (size_t)i * DS + 12);
        float corr = 0.0f;
        #pragma unroll
        for (int s = 0; s < 16; s++) {
            hd[s] *= pb[s];
            corr = fmaf(hd[s], Cv[s], corr);
        }
        float y = yp[(size_t)i * DI + d] + corr;
        float z = Z[(size_t)i * DI + d];
        ygb[(size_t)i * DI + d] = f2b(y * siluf_(z));
    }
}

// ----------------------- outproj (MFMA): x += ygb @ WbO^T  (residual add)
// M=32768 N=256 K=512, tile 128x128, BK=32.
__global__ __launch_bounds__(256) void k_outproj(
    const unsigned short* __restrict__ A, const unsigned short* __restrict__ W,
    float* __restrict__ x) {
    __shared__ unsigned short As[128 * 32];
    __shared__ unsigned short Bs[128 * 32];
    int tid = threadIdx.x, lane = tid & 63, wid = tid >> 6;
    int tileN = blockIdx.x & 1, tileM = blockIdx.x >> 1;
    int i0 = tileM * 128, n0 = tileN * 128;
    f32x4 acc[4][4];
    #pragma unroll
    for (int mi = 0; mi < 4; mi++)
        #pragma unroll
        for (int ni = 0; ni < 4; ni++) acc[mi][ni] = (f32x4){0.f, 0.f, 0.f, 0.f};

    int srow = (wid << 5) + (lane >> 2);
    int sblk = lane & 3;
    const unsigned short* ga = A + (size_t)(i0 + srow) * 512 + sblk * 8;
    const unsigned short* gb = W + (size_t)(n0 + srow) * 512 + sblk * 8;
    unsigned short* la = As + (wid << 5) * 32;
    unsigned short* lb = Bs + (wid << 5) * 32;
    int ar = lane & 15, ab = lane >> 4;
    const short8* pa = (const short8*)(As + ((wid >> 1) * 64 + ar) * 32 + ab * 8);
    const short8* pb = (const short8*)(Bs + ((wid & 1) * 64 + ar) * 32 + ab * 8);

    for (int k0 = 0; k0 < 512; k0 += 32) {
        gload_lds16(ga + k0,            la);
        gload_lds16(ga + k0 + 16 * 512, la + 16 * 32);
        gload_lds16(gb + k0,            lb);
        gload_lds16(gb + k0 + 16 * 512, lb + 16 * 32);
        __syncthreads();
        short8 a[4], b[4];
        #pragma unroll
        for (int mi = 0; mi < 4; mi++) a[mi] = pa[mi * 64];
        #pragma unroll
        for (int ni = 0; ni < 4; ni++) b[ni] = pb[ni * 64];
        #pragma unroll
        for (int mi = 0; mi < 4; mi++)
            #pragma unroll
            for (int ni = 0; ni < 4; ni++)
                acc[mi][ni] = __builtin_amdgcn_mfma_f32_16x16x32_bf16(a[mi], b[ni], acc[mi][ni], 0, 0, 0);
        __syncthreads();
    }
    int wr = wid >> 1, wc = wid & 1;
    int rbase = i0 + wr * 64 + (lane >> 4) * 4;
    int cbase = n0 + wc * 64 + (lane & 15);
    #pragma unroll
    for (int mi = 0; mi < 4; mi++)
        #pragma unroll
        for (int ni = 0; ni < 4; ni++)
            #pragma unroll
            for (int j = 0; j < 4; j++) {
                size_t idx = (size_t)(rbase + mi * 16 + j) * DM + cbase + ni * 16;
                x[idx] += acc[mi][ni][j];
            }
}

// -------------------------------------------- final LN + output projection
__global__ void k_final(const float* __restrict__ x, const float* __restrict__ gam,
                        const float* __restrict__ bet, const float* __restrict__ w,
                        const float* __restrict__ bias, float* __restrict__ out) {
    int lane = threadIdx.x & 63, wid = threadIdx.x >> 6;
    int i = blockIdx.x * 4 + wid;
    float4 v = *(const float4*)(x + (size_t)i * DM + lane * 4);
    float s = v.x + v.y + v.z + v.w;
    float q = v.x * v.x + v.y * v.y + v.z * v.z + v.w * v.w;
    #pragma unroll
    for (int m = 32; m; m >>= 1) { s += __shfl_xor(s, m, 64); q += __shfl_xor(q, m, 64); }
    float mu = s * (1.0f / DM);
    float rs = rsqrtf(q * (1.0f / DM) - mu * mu + EPSF);
    float4 gg = *(const float4*)(gam + lane * 4);
    float4 bb = *(const float4*)(bet + lane * 4);
    float xn[4] = {(v.x - mu) * rs * gg.x + bb.x, (v.y - mu) * rs * gg.y + bb.y,
                   (v.z - mu) * rs * gg.z + bb.z, (v.w - mu) * rs * gg.w + bb.w};
    float4 w0 = *(const float4*)(w + lane * 4);
    float4 w1 = *(const float4*)(w + DM + lane * 4);
    float p0 = xn[0] * w0.x + xn[1] * w0.y + xn[2] * w0.z + xn[3] * w0.w;
    float p1 = xn[0] * w1.x + xn[1] * w1.y + xn[2] * w1.z + xn[3] * w1.w;
    #pragma unroll
    for (int m = 32; m; m >>= 1) { p0 += __shfl_xor(p0, m, 64); p1 += __shfl_xor(p1, m, 64); }
    if (lane == 0) {
        out[(size_t)i * 2]     = p0 + bias[0];
        out[(size_t)i * 2 + 1] = p1 + bias[1];
    }
}

// ---------------------------------------------------------------------------
extern "C" void kernel_launch(void* const* d_in, const int* in_sizes, int n_in,
                              void* d_out, int out_size, void* d_ws, size_t ws_size,
                              hipStream_t stream) {
    const float* z_seq     = (const float*)d_in[0];
    const float* ip_w      = (const float*)d_in[1];
    const float* ip_b      = (const float*)d_in[2];
    const float* norm_g    = (const float*)d_in[3];
    const float* norm_b    = (const float*)d_in[4];
    const float* inproj_w  = (const float*)d_in[5];
    const float* conv_w    = (const float*)d_in[6];
    const float* conv_b    = (const float*)d_in[7];
    const float* xproj_w   = (const float*)d_in[8];
    const float* dt_w      = (const float*)d_in[9];
    const float* dt_b      = (const float*)d_in[10];
    const float* outproj_w = (const float*)d_in[11];
    const float* onorm_g   = (const float*)d_in[12];
    const float* onorm_b   = (const float*)d_in[13];
    const float* op_w      = (const float*)d_in[14];
    const float* op_b      = (const float*)d_in[15];

    char* ws = (char*)d_ws;
    float* x    = (float*)(ws + OFF_X);
    float* Zb   = (float*)(ws + OFF_Z);
    float* xc   = (float*)(ws + OFF_XC);
    unsigned short* xpb = (unsigned short*)(ws + OFF_XPB);
    unsigned short* xln = (unsigned short*)(ws + OFF_XLN);
    float* Bmb  = (float*)(ws + OFF_B);
    float* Cmb  = (float*)(ws + OFF_C);
    float* dtrb = (float*)(ws + OFF_DTR);
    float* hend = (float*)(ws + OFF_HE);
    float* dtc  = (float*)(ws + OFF_DTC);
    unsigned short* WbI = (unsigned short*)(ws + OFF_WB);
    unsigned short* WbO = WbI + WBI_EL;

    // one-time weight conversion (graph-safe: same work every call)
    k_cvt<<<(WBI_EL / 4 + 255) / 256, 256, 0, stream>>>(inproj_w,  WbI, (int)WBI_EL);
    k_cvt<<<(WBO_EL / 4 + 255) / 256, 256, 0, stream>>>(outproj_w, WbO, (int)WBO_EL);

    k_inproj<<<NTOK * DM / 256, 256, 0, stream>>>(z_seq, ip_w, ip_b, x);

    for (int l = 0; l < 2; l++) {
        k_lnrow<<<NTOK / 4, 256, 0, stream>>>(x, norm_g + l * DM, norm_b + l * DM, xln);
        k_gemm1<<<(NTOK / 128) * 8, 256, 0, stream>>>(
            xln, WbI + (size_t)l * 2 * DI * DM, xpb, Zb);
        k_conv<<<NTOK * (DI / 4) / 256, 256, 0, stream>>>(
            xpb, conv_w + (size_t)l * DI * 4, conv_b + (size_t)l * DI, xc);
        k_xproj<<<NTOK / 32, 256, 0, stream>>>(
            xc, xproj_w + (size_t)l * 33 * DI, Bmb, Cmb, dtrb);
        k_scan1<<<BATCH * DI * NCH / 256, 256, 0, stream>>>(
            xc, Bmb, Cmb, dtrb, dt_w + l * DI, dt_b + l * DI, hend, dtc);
        k_scan2<<<BATCH * DI / 256, 256, 0, stream>>>(hend, dtc);
        k_scan3<<<BATCH * DI * NCH / 256, 256, 0, stream>>>(
            Cmb, dtrb, dt_w + l * DI, dt_b + l * DI, hend, xc, Zb, xpb);
        k_outproj<<<(NTOK / 128) * 2, 256, 0, stream>>>(
            xpb, WbO + (size_t)l * DM * DI, x);
    }
    k_final<<<NTOK / 4, 256, 0, stream>>>(x, onorm_g, onorm_b, op_w, op_b, (float*)d_out);
}

// Round 4
// 718.920 us; speedup vs baseline: 2.6951x; 1.6843x over previous
//
#include <hip/hip_runtime.h>
#include <cstddef>
#include <cstdint>

#define DEV __device__ __forceinline__

namespace {
constexpr int BATCH = 8;
constexpr int SEQL  = 4096;
constexpr int DM    = 256;   // d_model
constexpr int DS    = 16;    // d_state
constexpr int DI    = 512;   // d_inner
constexpr int NTOK  = BATCH * SEQL;   // 32768
constexpr int TC    = 64;             // scan chunk length
constexpr int NCH   = SEQL / TC;      // 64 chunks per sequence
constexpr float EPSF = 1e-5f;

// workspace offsets (bytes)
constexpr size_t OFF_X   = 0;                                   // fp32 NTOK*DM
constexpr size_t OFF_XPB = OFF_X   + (size_t)NTOK * DM * 4;     // bf16 NTOK*DI (xp -> ygb)
constexpr size_t OFF_ZBB = OFF_XPB + (size_t)NTOK * DI * 2;     // bf16 NTOK*DI (z)
constexpr size_t OFF_XCB = OFF_ZBB + (size_t)NTOK * DI * 2;     // bf16 NTOK*DI (conv out)
constexpr size_t OFF_XLN = OFF_XCB + (size_t)NTOK * DI * 2;     // bf16 NTOK*DM
constexpr size_t OFF_B   = OFF_XLN + (size_t)NTOK * DM * 2;     // fp32 NTOK*DS
constexpr size_t OFF_C   = OFF_B   + (size_t)NTOK * DS * 4;     // fp32 NTOK*DS
constexpr size_t OFF_DTR = OFF_C   + (size_t)NTOK * DS * 4;     // fp32 NTOK
constexpr size_t OFF_HE  = OFF_DTR + (size_t)NTOK * 4;          // fp32 BATCH*DI*NCH*DS
constexpr size_t OFF_DTC = OFF_HE  + (size_t)BATCH * DI * NCH * DS * 4; // fp32 BATCH*DI*NCH
constexpr size_t OFF_WBI = OFF_DTC + (size_t)BATCH * DI * NCH * 4;      // bf16 2*1024*256
constexpr size_t OFF_WBO = OFF_WBI + (size_t)2 * 2 * DI * DM * 2;       // bf16 2*256*512
constexpr size_t OFF_WBX = OFF_WBO + (size_t)2 * DM * DI * 2;           // bf16 2*48*512 (padded)
constexpr size_t WBI_EL  = 2 * 2 * DI * DM;   // 524288
constexpr size_t WBO_EL  = 2 * DM * DI;       // 262144
} // namespace

typedef __attribute__((ext_vector_type(8))) short short8;
typedef __attribute__((ext_vector_type(4))) float f32x4;

DEV float sigmoidf_(float v) { return 1.0f / (1.0f + __expf(-v)); }
DEV float siluf_(float v)    { return v * sigmoidf_(v); }
DEV float softplusf_(float v) {
    return fmaxf(v, 0.0f) + __logf(1.0f + __expf(-fabsf(v)));
}
DEV float b2f(unsigned short u) {
    union { unsigned int i; float f; } c; c.i = ((unsigned int)u) << 16; return c.f;
}
DEV unsigned short f2b(float f) {  // round-to-nearest-even
    union { float f; unsigned int i; } c; c.f = f;
    unsigned int lsb = (c.i >> 16) & 1u;
    c.i += 0x7fffu + lsb;
    return (unsigned short)(c.i >> 16);
}
DEV void pows16(float p, float* pb) {  // pb[s] = p^(s+1), dep-depth ~4
    float p2 = p * p, p4 = p2 * p2, p8 = p4 * p4;
    pb[0] = p;        pb[1] = p2;       pb[2] = p2 * p;      pb[3] = p4;
    pb[4] = p4 * p;   pb[5] = p4 * p2;  pb[6] = p4 * p2 * p; pb[7] = p8;
    pb[8] = p8 * p;   pb[9] = p8 * p2;  pb[10] = p8 * p2 * p; pb[11] = p8 * p4;
    pb[12] = p8 * p4 * p; pb[13] = p8 * p4 * p2; pb[14] = p8 * p4 * p2 * p; pb[15] = p8 * p8;
}
DEV void gload_lds16(const unsigned short* g, unsigned short* l) {
    __builtin_amdgcn_global_load_lds(
        (__attribute__((address_space(1))) void*)(g),
        (__attribute__((address_space(3))) void*)(l), 16, 0, 0);
}

// ------------------------------------------------------------- f32 -> bf16
__global__ void k_cvt(const float* __restrict__ src, unsigned short* __restrict__ dst, int n) {
    int g = (blockIdx.x * 256 + threadIdx.x) * 4;
    if (g >= n) return;
    float4 v = *(const float4*)(src + g);
    ushort4 o;
    o.x = f2b(v.x); o.y = f2b(v.y); o.z = f2b(v.z); o.w = f2b(v.w);
    *(ushort4*)(dst + g) = o;
}

// ------------------------------------ xproj weights: [2][33][512] -> padded [2][48][512] bf16
__global__ void k_cvtx(const float* __restrict__ src, unsigned short* __restrict__ dst) {
    int idx = blockIdx.x * 256 + threadIdx.x;      // 2*48*512 = 49152
    int l = idx / (48 * 512), r = (idx >> 9) % 48, cc = idx & 511;
    dst[idx] = (r < 33) ? f2b(src[(size_t)(l * 33 + r) * 512 + cc]) : (unsigned short)0;
}

// ---------------------------------------------------------------- input proj
__global__ void k_inproj(const float* __restrict__ z, const float* __restrict__ w,
                         const float* __restrict__ bias, float* __restrict__ x) {
    int g = blockIdx.x * 256 + threadIdx.x;     // NTOK*DM threads
    int i = g >> 8, m = g & 255;
    float4 zv = *(const float4*)(z + (size_t)i * 4);
    float4 wv = *(const float4*)(w + (size_t)m * 4);
    float r = bias[m];
    r = fmaf(zv.x, wv.x, r);
    r = fmaf(zv.y, wv.y, r);
    r = fmaf(zv.z, wv.z, r);
    r = fmaf(zv.w, wv.w, r);
    x[g] = r;
}

// -------------------------------------------- fused row-LN -> bf16 (per wave)
__global__ void k_lnrow(const float* __restrict__ x, const float* __restrict__ gam,
                        const float* __restrict__ bet, unsigned short* __restrict__ xln) {
    int lane = threadIdx.x & 63, wid = threadIdx.x >> 6;
    int i = blockIdx.x * 4 + wid;
    float4 v = *(const float4*)(x + (size_t)i * DM + lane * 4);
    float s = v.x + v.y + v.z + v.w;
    float q = v.x * v.x + v.y * v.y + v.z * v.z + v.w * v.w;
    #pragma unroll
    for (int m = 32; m; m >>= 1) { s += __shfl_xor(s, m, 64); q += __shfl_xor(q, m, 64); }
    float mu = s * (1.0f / DM);
    float rs = rsqrtf(q * (1.0f / DM) - mu * mu + EPSF);
    float4 g4 = *(const float4*)(gam + lane * 4);
    float4 b4 = *(const float4*)(bet + lane * 4);
    ushort4 o;
    o.x = f2b((v.x - mu) * rs * g4.x + b4.x);
    o.y = f2b((v.y - mu) * rs * g4.y + b4.y);
    o.z = f2b((v.z - mu) * rs * g4.z + b4.z);
    o.w = f2b((v.w - mu) * rs * g4.w + b4.w);
    *(ushort4*)(xln + (size_t)i * DM + lane * 4) = o;
}

// ------------------------------------- GEMM1 (MFMA): [xp|z] = xln @ WbI^T
// M=32768 N=1024 K=256, tile 128x128, BK=32. N<512 -> xpb, else -> zbb (both bf16)
__global__ __launch_bounds__(256) void k_gemm1(
    const unsigned short* __restrict__ A, const unsigned short* __restrict__ W,
    unsigned short* __restrict__ xpb, unsigned short* __restrict__ zbb) {
    __shared__ unsigned short As[128 * 32];
    __shared__ unsigned short Bs[128 * 32];
    int tid = threadIdx.x, lane = tid & 63, wid = tid >> 6;
    int tileN = blockIdx.x & 7, tileM = blockIdx.x >> 3;
    int i0 = tileM * 128, n0 = tileN * 128;
    f32x4 acc[4][4];
    #pragma unroll
    for (int mi = 0; mi < 4; mi++)
        #pragma unroll
        for (int ni = 0; ni < 4; ni++) acc[mi][ni] = (f32x4){0.f, 0.f, 0.f, 0.f};

    int srow = (wid << 5) + (lane >> 2);
    int sblk = lane & 3;
    const unsigned short* ga = A + (size_t)(i0 + srow) * 256 + sblk * 8;
    const unsigned short* gb = W + (size_t)(n0 + srow) * 256 + sblk * 8;
    unsigned short* la = As + (wid << 5) * 32;
    unsigned short* lb = Bs + (wid << 5) * 32;
    int ar = lane & 15, ab = lane >> 4;
    const short8* pa = (const short8*)(As + ((wid >> 1) * 64 + ar) * 32 + ab * 8);
    const short8* pb = (const short8*)(Bs + ((wid & 1) * 64 + ar) * 32 + ab * 8);

    for (int k0 = 0; k0 < 256; k0 += 32) {
        gload_lds16(ga + k0,            la);
        gload_lds16(ga + k0 + 16 * 256, la + 16 * 32);
        gload_lds16(gb + k0,            lb);
        gload_lds16(gb + k0 + 16 * 256, lb + 16 * 32);
        __syncthreads();
        short8 a[4], b[4];
        #pragma unroll
        for (int mi = 0; mi < 4; mi++) a[mi] = pa[mi * 64];
        #pragma unroll
        for (int ni = 0; ni < 4; ni++) b[ni] = pb[ni * 64];
        #pragma unroll
        for (int mi = 0; mi < 4; mi++)
            #pragma unroll
            for (int ni = 0; ni < 4; ni++)
                acc[mi][ni] = __builtin_amdgcn_mfma_f32_16x16x32_bf16(a[mi], b[ni], acc[mi][ni], 0, 0, 0);
        __syncthreads();
    }
    int wr = wid >> 1, wc = wid & 1;
    int rbase = i0 + wr * 64 + (lane >> 4) * 4;
    int cbase = n0 + wc * 64 + (lane & 15);
    unsigned short* dst = (n0 < 512) ? xpb : zbb;
    int coff = (n0 < 512) ? cbase : cbase - 512;
    #pragma unroll
    for (int mi = 0; mi < 4; mi++)
        #pragma unroll
        for (int ni = 0; ni < 4; ni++)
            #pragma unroll
            for (int j = 0; j < 4; j++)
                dst[(size_t)(rbase + mi * 16 + j) * 512 + coff + ni * 16] = f2b(acc[mi][ni][j]);
}

// -------------------------------- depthwise causal conv + SiLU -> bf16 xcb
__global__ void k_conv(const unsigned short* __restrict__ xpb, const float* __restrict__ cw,
                       const float* __restrict__ cb, unsigned short* __restrict__ xcb) {
    int g = blockIdx.x * 256 + threadIdx.x;     // NTOK*128 threads
    int i = g >> 7, dq = g & 127;
    int t = i & (SEQL - 1);
    int d = dq * 4;
    float4 acc = *(const float4*)(cb + d);
    #pragma unroll
    for (int k = 0; k < 4; k++) {
        int tt = t + k - 3;
        if (tt >= 0) {
            ushort4 v = *(const ushort4*)(xpb + (size_t)(i + k - 3) * 512 + d);
            acc.x = fmaf(b2f(v.x), cw[(d + 0) * 4 + k], acc.x);
            acc.y = fmaf(b2f(v.y), cw[(d + 1) * 4 + k], acc.y);
            acc.z = fmaf(b2f(v.z), cw[(d + 2) * 4 + k], acc.z);
            acc.w = fmaf(b2f(v.w), cw[(d + 3) * 4 + k], acc.w);
        }
    }
    ushort4 o;
    o.x = f2b(siluf_(acc.x)); o.y = f2b(siluf_(acc.y));
    o.z = f2b(siluf_(acc.z)); o.w = f2b(siluf_(acc.w));
    *(ushort4*)(xcb + (size_t)i * DI + d) = o;
}

// --------------------- xproj (MFMA): ssm = xcb @ WX_pad^T (N=48, rows>=33 dead)
// M=32768 N=48 K=512, tile 128x48, BK=32, 4 waves (wave w: rows w*32..w*32+31)
__global__ __launch_bounds__(256) void k_xprojm(
    const unsigned short* __restrict__ A, const unsigned short* __restrict__ W,
    float* __restrict__ Bm, float* __restrict__ Cm, float* __restrict__ dtr) {
    __shared__ unsigned short As[128 * 32];
    __shared__ unsigned short Bs[48 * 32];
    int tid = threadIdx.x, lane = tid & 63, wid = tid >> 6;
    int i0 = blockIdx.x * 128;
    f32x4 acc[2][3];
    #pragma unroll
    for (int mi = 0; mi < 2; mi++)
        #pragma unroll
        for (int ni = 0; ni < 3; ni++) acc[mi][ni] = (f32x4){0.f, 0.f, 0.f, 0.f};

    int srow = lane >> 2, sblk = lane & 3;
    const unsigned short* ga = A + (size_t)(i0 + (wid << 5) + srow) * 512 + sblk * 8;
    unsigned short* la = As + (wid << 5) * 32;
    const unsigned short* gb = W + (size_t)((wid << 4) + srow) * 512 + sblk * 8;
    unsigned short* lb = Bs + (wid << 4) * 32;
    int ar = lane & 15, ab = lane >> 4;

    for (int k0 = 0; k0 < 512; k0 += 32) {
        gload_lds16(ga + k0,            la);
        gload_lds16(ga + k0 + 16 * 512, la + 16 * 32);
        if (wid < 3) gload_lds16(gb + k0, lb);
        __syncthreads();
        short8 a[2], b[3];
        #pragma unroll
        for (int mi = 0; mi < 2; mi++)
            a[mi] = *(const short8*)(As + ((wid << 5) + mi * 16 + ar) * 32 + ab * 8);
        #pragma unroll
        for (int ni = 0; ni < 3; ni++)
            b[ni] = *(const short8*)(Bs + (ni * 16 + ar) * 32 + ab * 8);
        #pragma unroll
        for (int mi = 0; mi < 2; mi++)
            #pragma unroll
            for (int ni = 0; ni < 3; ni++)
                acc[mi][ni] = __builtin_amdgcn_mfma_f32_16x16x32_bf16(a[mi], b[ni], acc[mi][ni], 0, 0, 0);
        __syncthreads();
    }
    #pragma unroll
    for (int mi = 0; mi < 2; mi++)
        #pragma unroll
        for (int ni = 0; ni < 3; ni++)
            #pragma unroll
            for (int j = 0; j < 4; j++) {
                int row = i0 + (wid << 5) + mi * 16 + (lane >> 4) * 4 + j;
                int ng = ni * 16 + (lane & 15);
                float v = acc[mi][ni][j];
                if (ng < 16)       Bm[(size_t)row * DS + ng] = v;
                else if (ng < 32)  Cm[(size_t)row * DS + ng - 16] = v;
                else if (ng == 32) dtr[row] = v;
            }
}

// ---------------- scan phase 1: chunk-local end states only (no y)
// block = (b, c, half): 256 threads = 256 channels; B rows + dtr staged in LDS
__global__ __launch_bounds__(256) void k_scan1(
    const unsigned short* __restrict__ xcb, const float* __restrict__ Bm,
    const float* __restrict__ dtr, const float* __restrict__ dw,
    const float* __restrict__ db, float* __restrict__ hend, float* __restrict__ dtc) {
    __shared__ float Bsh[64][16];
    __shared__ float dtl[64];
    int tid = threadIdx.x;
    int blk = blockIdx.x;                       // ((b*NCH)+c)*2 + half
    int half = blk & 1, c = (blk >> 1) & (NCH - 1), b = blk >> 7;
    int d = half * 256 + tid;
    int i0 = (b << 12) + c * TC;
    if (tid < 64) dtl[tid] = dtr[i0 + tid];
    {
        int idx = tid * 4, tt = idx >> 4, ss = idx & 15;
        *(float4*)(&Bsh[tt][ss]) = *(const float4*)(Bm + (size_t)(i0 + tt) * DS + ss);
    }
    __syncthreads();
    float dwd = dw[d], dbd = db[d];
    float h[16];
    #pragma unroll
    for (int s = 0; s < 16; s++) h[s] = 0.0f;
    float dtsum = 0.0f;
    for (int t = 0; t < TC; t++) {
        float dt = softplusf_(fmaf(dtl[t], dwd, dbd));
        dtsum += dt;
        float p = __expf(-dt);
        float pb[16];
        pows16(p, pb);
        float x = b2f(xcb[(size_t)(i0 + t) * DI + d]);
        float dtx = dt * x;
        float Bv[16];
        *(float4*)(Bv + 0)  = *(const float4*)(&Bsh[t][0]);
        *(float4*)(Bv + 4)  = *(const float4*)(&Bsh[t][4]);
        *(float4*)(Bv + 8)  = *(const float4*)(&Bsh[t][8]);
        *(float4*)(Bv + 12) = *(const float4*)(&Bsh[t][12]);
        #pragma unroll
        for (int s = 0; s < 16; s++) h[s] = fmaf(pb[s], h[s], dtx * Bv[s]);
    }
    size_t hb = ((size_t)(b * DI + d) * NCH + c) * DS;
    #pragma unroll
    for (int s = 0; s < 16; s += 4)
        *(float4*)(hend + hb + s) = make_float4(h[s], h[s + 1], h[s + 2], h[s + 3]);
    dtc[(size_t)(b * DI + d) * NCH + c] = dtsum;
}

// ------------- scan phase 2: propagate chunk-entry states; thread per (b,d,s)
__global__ void k_scan2(float* __restrict__ hend, const float* __restrict__ dtc) {
    int g = blockIdx.x * 256 + threadIdx.x;     // BATCH*DI*DS = 65536
    int s = g & 15, dd = (g >> 4) & 511, b = g >> 13;
    size_t base = (size_t)(b * DI + dd) * NCH;
    float hin = 0.0f;
    float kneg = -(float)(s + 1);
    #pragma unroll 4
    for (int c = 0; c < NCH; c++) {
        size_t a = (base + c) * DS + s;
        float tmp = hend[a];
        float pb = __expf(kneg * dtc[base + c]);
        hend[a] = hin;
        hin = fmaf(pb, hin, tmp);
    }
}

// -------- scan phase 3: recompute recurrence from entry state, gate, write bf16
__global__ __launch_bounds__(256) void k_scan3(
    const unsigned short* __restrict__ xcb, const float* __restrict__ Bm,
    const float* __restrict__ Cm, const float* __restrict__ dtr,
    const float* __restrict__ dw, const float* __restrict__ db,
    const float* __restrict__ hend, const unsigned short* __restrict__ zbb,
    unsigned short* __restrict__ ygb) {
    __shared__ float Bsh[64][16];
    __shared__ float Csh[64][16];
    __shared__ float dtl[64];
    int tid = threadIdx.x;
    int blk = blockIdx.x;
    int half = blk & 1, c = (blk >> 1) & (NCH - 1), b = blk >> 7;
    int d = half * 256 + tid;
    int i0 = (b << 12) + c * TC;
    if (tid < 64) dtl[tid] = dtr[i0 + tid];
    {
        int idx = tid * 4, tt = idx >> 4, ss = idx & 15;
        *(float4*)(&Bsh[tt][ss]) = *(const float4*)(Bm + (size_t)(i0 + tt) * DS + ss);
        *(float4*)(&Csh[tt][ss]) = *(const float4*)(Cm + (size_t)(i0 + tt) * DS + ss);
    }
    __syncthreads();
    float dwd = dw[d], dbd = db[d];
    float h[16];
    size_t hb = ((size_t)(b * DI + d) * NCH + c) * DS;
    #pragma unroll
    for (int s = 0; s < 16; s += 4) *(float4*)(h + s) = *(const float4*)(hend + hb + s);
    for (int t = 0; t < TC; t++) {
        float dt = softplusf_(fmaf(dtl[t], dwd, dbd));
        float p = __expf(-dt);
        float pb[16];
        pows16(p, pb);
        size_t gi = (size_t)(i0 + t) * DI + d;
        float x = b2f(xcb[gi]);
        float dtx = dt * x;
        float Bv[16], Cv[16];
        *(float4*)(Bv + 0)  = *(const float4*)(&Bsh[t][0]);
        *(float4*)(Bv + 4)  = *(const float4*)(&Bsh[t][4]);
        *(float4*)(Bv + 8)  = *(const float4*)(&Bsh[t][8]);
        *(float4*)(Bv + 12) = *(const float4*)(&Bsh[t][12]);
        *(float4*)(Cv + 0)  = *(const float4*)(&Csh[t][0]);
        *(float4*)(Cv + 4)  = *(const float4*)(&Csh[t][4]);
        *(float4*)(Cv + 8)  = *(const float4*)(&Csh[t][8]);
        *(float4*)(Cv + 12) = *(const float4*)(&Csh[t][12]);
        float y = 0.0f;
        #pragma unroll
        for (int s = 0; s < 16; s++) {
            h[s] = fmaf(pb[s], h[s], dtx * Bv[s]);
            y = fmaf(h[s], Cv[s], y);
        }
        float z = b2f(zbb[gi]);
        ygb[gi] = f2b(y * siluf_(z));
    }
}

// ----------------------- outproj (MFMA): x += ygb @ WbO^T  (residual add)
__global__ __launch_bounds__(256) void k_outproj(
    const unsigned short* __restrict__ A, const unsigned short* __restrict__ W,
    float* __restrict__ x) {
    __shared__ unsigned short As[128 * 32];
    __shared__ unsigned short Bs[128 * 32];
    int tid = threadIdx.x, lane = tid & 63, wid = tid >> 6;
    int tileN = blockIdx.x & 1, tileM = blockIdx.x >> 1;
    int i0 = tileM * 128, n0 = tileN * 128;
    f32x4 acc[4][4];
    #pragma unroll
    for (int mi = 0; mi < 4; mi++)
        #pragma unroll
        for (int ni = 0; ni < 4; ni++) acc[mi][ni] = (f32x4){0.f, 0.f, 0.f, 0.f};

    int srow = (wid << 5) + (lane >> 2);
    int sblk = lane & 3;
    const unsigned short* ga = A + (size_t)(i0 + srow) * 512 + sblk * 8;
    const unsigned short* gb = W + (size_t)(n0 + srow) * 512 + sblk * 8;
    unsigned short* la = As + (wid << 5) * 32;
    unsigned short* lb = Bs + (wid << 5) * 32;
    int ar = lane & 15, ab = lane >> 4;
    const short8* pa = (const short8*)(As + ((wid >> 1) * 64 + ar) * 32 + ab * 8);
    const short8* pb = (const short8*)(Bs + ((wid & 1) * 64 + ar) * 32 + ab * 8);

    for (int k0 = 0; k0 < 512; k0 += 32) {
        gload_lds16(ga + k0,            la);
        gload_lds16(ga + k0 + 16 * 512, la + 16 * 32);
        gload_lds16(gb + k0,            lb);
        gload_lds16(gb + k0 + 16 * 512, lb + 16 * 32);
        __syncthreads();
        short8 a[4], b[4];
        #pragma unroll
        for (int mi = 0; mi < 4; mi++) a[mi] = pa[mi * 64];
        #pragma unroll
        for (int ni = 0; ni < 4; ni++) b[ni] = pb[ni * 64];
        #pragma unroll
        for (int mi = 0; mi < 4; mi++)
            #pragma unroll
            for (int ni = 0; ni < 4; ni++)
                acc[mi][ni] = __builtin_amdgcn_mfma_f32_16x16x32_bf16(a[mi], b[ni], acc[mi][ni], 0, 0, 0);
        __syncthreads();
    }
    int wr = wid >> 1, wc = wid & 1;
    int rbase = i0 + wr * 64 + (lane >> 4) * 4;
    int cbase = n0 + wc * 64 + (lane & 15);
    #pragma unroll
    for (int mi = 0; mi < 4; mi++)
        #pragma unroll
        for (int ni = 0; ni < 4; ni++)
            #pragma unroll
            for (int j = 0; j < 4; j++) {
                size_t idx = (size_t)(rbase + mi * 16 + j) * DM + cbase + ni * 16;
                x[idx] += acc[mi][ni][j];
            }
}

// -------------------------------------------- final LN + output projection
__global__ void k_final(const float* __restrict__ x, const float* __restrict__ gam,
                        const float* __restrict__ bet, const float* __restrict__ w,
                        const float* __restrict__ bias, float* __restrict__ out) {
    int lane = threadIdx.x & 63, wid = threadIdx.x >> 6;
    int i = blockIdx.x * 4 + wid;
    float4 v = *(const float4*)(x + (size_t)i * DM + lane * 4);
    float s = v.x + v.y + v.z + v.w;
    float q = v.x * v.x + v.y * v.y + v.z * v.z + v.w * v.w;
    #pragma unroll
    for (int m = 32; m; m >>= 1) { s += __shfl_xor(s, m, 64); q += __shfl_xor(q, m, 64); }
    float mu = s * (1.0f / DM);
    float rs = rsqrtf(q * (1.0f / DM) - mu * mu + EPSF);
    float4 gg = *(const float4*)(gam + lane * 4);
    float4 bb = *(const float4*)(bet + lane * 4);
    float xn[4] = {(v.x - mu) * rs * gg.x + bb.x, (v.y - mu) * rs * gg.y + bb.y,
                   (v.z - mu) * rs * gg.z + bb.z, (v.w - mu) * rs * gg.w + bb.w};
    float4 w0 = *(const float4*)(w + lane * 4);
    float4 w1 = *(const float4*)(w + DM + lane * 4);
    float p0 = xn[0] * w0.x + xn[1] * w0.y + xn[2] * w0.z + xn[3] * w0.w;
    float p1 = xn[0] * w1.x + xn[1] * w1.y + xn[2] * w1.z + xn[3] * w1.w;
    #pragma unroll
    for (int m = 32; m; m >>= 1) { p0 += __shfl_xor(p0, m, 64); p1 += __shfl_xor(p1, m, 64); }
    if (lane == 0) {
        out[(size_t)i * 2]     = p0 + bias[0];
        out[(size_t)i * 2 + 1] = p1 + bias[1];
    }
}

// ---------------------------------------------------------------------------
extern "C" void kernel_launch(void* const* d_in, const int* in_sizes, int n_in,
                              void* d_out, int out_size, void* d_ws, size_t ws_size,
                              hipStream_t stream) {
    const float* z_seq     = (const float*)d_in[0];
    const float* ip_w      = (const float*)d_in[1];
    const float* ip_b      = (const float*)d_in[2];
    const float* norm_g    = (const float*)d_in[3];
    const float* norm_b    = (const float*)d_in[4];
    const float* inproj_w  = (const float*)d_in[5];
    const float* conv_w    = (const float*)d_in[6];
    const float* conv_b    = (const float*)d_in[7];
    const float* xproj_w   = (const float*)d_in[8];
    const float* dt_w      = (const float*)d_in[9];
    const float* dt_b      = (const float*)d_in[10];
    const float* outproj_w = (const float*)d_in[11];
    const float* onorm_g   = (const float*)d_in[12];
    const float* onorm_b   = (const float*)d_in[13];
    const float* op_w      = (const float*)d_in[14];
    const float* op_b      = (const float*)d_in[15];

    char* ws = (char*)d_ws;
    float* x    = (float*)(ws + OFF_X);
    unsigned short* xpb = (unsigned short*)(ws + OFF_XPB);
    unsigned short* zbb = (unsigned short*)(ws + OFF_ZBB);
    unsigned short* xcb = (unsigned short*)(ws + OFF_XCB);
    unsigned short* xln = (unsigned short*)(ws + OFF_XLN);
    float* Bmb  = (float*)(ws + OFF_B);
    float* Cmb  = (float*)(ws + OFF_C);
    float* dtrb = (float*)(ws + OFF_DTR);
    float* hend = (float*)(ws + OFF_HE);
    float* dtc  = (float*)(ws + OFF_DTC);
    unsigned short* WbI = (unsigned short*)(ws + OFF_WBI);
    unsigned short* WbO = (unsigned short*)(ws + OFF_WBO);
    unsigned short* WbX = (unsigned short*)(ws + OFF_WBX);

    k_cvt<<<(int)(WBI_EL / 4 / 256), 256, 0, stream>>>(inproj_w,  WbI, (int)WBI_EL);
    k_cvt<<<(int)(WBO_EL / 4 / 256), 256, 0, stream>>>(outproj_w, WbO, (int)WBO_EL);
    k_cvtx<<<2 * 48 * 512 / 256, 256, 0, stream>>>(xproj_w, WbX);

    k_inproj<<<NTOK * DM / 256, 256, 0, stream>>>(z_seq, ip_w, ip_b, x);

    for (int l = 0; l < 2; l++) {
        k_lnrow<<<NTOK / 4, 256, 0, stream>>>(x, norm_g + l * DM, norm_b + l * DM, xln);
        k_gemm1<<<(NTOK / 128) * 8, 256, 0, stream>>>(
            xln, WbI + (size_t)l * 2 * DI * DM, xpb, zbb);
        k_conv<<<NTOK * (DI / 4) / 256, 256, 0, stream>>>(
            xpb, conv_w + (size_t)l * DI * 4, conv_b + (size_t)l * DI, xcb);
        k_xprojm<<<NTOK / 128, 256, 0, stream>>>(
            xcb, WbX + (size_t)l * 48 * DI, Bmb, Cmb, dtrb);
        k_scan1<<<BATCH * NCH * 2, 256, 0, stream>>>(
            xcb, Bmb, dtrb, dt_w + l * DI, dt_b + l * DI, hend, dtc);
        k_scan2<<<BATCH * DI * DS / 256, 256, 0, stream>>>(hend, dtc);
        k_scan3<<<BATCH * NCH * 2, 256, 0, stream>>>(
            xcb, Bmb, Cmb, dtrb, dt_w + l * DI, dt_b + l * DI, hend, zbb, xpb);
        k_outproj<<<(NTOK / 128) * 2, 256, 0, stream>>>(
            xpb, WbO + (size_t)l * DM * DI, x);
    }
    k_final<<<NTOK / 4, 256, 0, stream>>>(x, onorm_g, onorm_b, op_w, op_b, (float*)d_out);
}

// Round 5
// 509.034 us; speedup vs baseline: 3.8064x; 1.4123x over previous
//
#include <hip/hip_runtime.h>
#include <cstddef>
#include <cstdint>

#define DEV __device__ __forceinline__

namespace {
constexpr int BATCH = 8;
constexpr int SEQL  = 4096;
constexpr int DM    = 256;   // d_model
constexpr int DS    = 16;    // d_state
constexpr int DI    = 512;   // d_inner
constexpr int NTOK  = BATCH * SEQL;   // 32768
constexpr int TC    = 64;             // scan chunk length
constexpr int NCH   = SEQL / TC;      // 64 chunks per sequence
constexpr float EPSF = 1e-5f;

// workspace offsets (bytes)
constexpr size_t OFF_X   = 0;                                   // fp32 NTOK*DM
constexpr size_t OFF_XPB = OFF_X   + (size_t)NTOK * DM * 4;     // bf16 NTOK*DI (xp -> ygb)
constexpr size_t OFF_ZBB = OFF_XPB + (size_t)NTOK * DI * 2;     // bf16 NTOK*DI (z)
constexpr size_t OFF_XCB = OFF_ZBB + (size_t)NTOK * DI * 2;     // bf16 NTOK*DI (conv out)
constexpr size_t OFF_XLN = OFF_XCB + (size_t)NTOK * DI * 2;     // bf16 NTOK*DM
constexpr size_t OFF_B   = OFF_XLN + (size_t)NTOK * DM * 2;     // fp32 NTOK*DS
constexpr size_t OFF_C   = OFF_B   + (size_t)NTOK * DS * 4;     // fp32 NTOK*DS
constexpr size_t OFF_DTR = OFF_C   + (size_t)NTOK * DS * 4;     // fp32 NTOK
constexpr size_t OFF_HE  = OFF_DTR + (size_t)NTOK * 4;          // fp32 BATCH*DI*NCH*DS
constexpr size_t OFF_DTC = OFF_HE  + (size_t)BATCH * DI * NCH * DS * 4; // fp32 BATCH*DI*NCH
constexpr size_t OFF_WBI = OFF_DTC + (size_t)BATCH * DI * NCH * 4;      // bf16 2*1024*256
constexpr size_t OFF_WBO = OFF_WBI + (size_t)2 * 2 * DI * DM * 2;       // bf16 2*256*512
constexpr size_t OFF_WBX = OFF_WBO + (size_t)2 * DM * DI * 2;           // bf16 2*48*512 (padded)
constexpr size_t OFF_CWT = OFF_WBX + (size_t)2 * 48 * DI * 2;           // fp32 2*4*512 transposed conv w
constexpr size_t WBI_EL  = 2 * 2 * DI * DM;   // 524288
constexpr size_t WBO_EL  = 2 * DM * DI;       // 262144
} // namespace

typedef __attribute__((ext_vector_type(8))) short short8;
typedef __attribute__((ext_vector_type(4))) float f32x4;

DEV float sigmoidf_(float v) { return 1.0f / (1.0f + __expf(-v)); }
DEV float siluf_(float v)    { return v * sigmoidf_(v); }
DEV float softplusf_(float v) {
    return fmaxf(v, 0.0f) + __logf(1.0f + __expf(-fabsf(v)));
}
DEV float b2f(unsigned short u) {
    union { unsigned int i; float f; } c; c.i = ((unsigned int)u) << 16; return c.f;
}
DEV float4 b4f(ushort4 u) {
    return make_float4(b2f(u.x), b2f(u.y), b2f(u.z), b2f(u.w));
}
DEV unsigned short f2b(float f) {  // round-to-nearest-even
    union { float f; unsigned int i; } c; c.f = f;
    unsigned int lsb = (c.i >> 16) & 1u;
    c.i += 0x7fffu + lsb;
    return (unsigned short)(c.i >> 16);
}
DEV void pows16(float p, float* pb) {  // pb[s] = p^(s+1), dep-depth ~4
    float p2 = p * p, p4 = p2 * p2, p8 = p4 * p4;
    pb[0] = p;        pb[1] = p2;       pb[2] = p2 * p;      pb[3] = p4;
    pb[4] = p4 * p;   pb[5] = p4 * p2;  pb[6] = p4 * p2 * p; pb[7] = p8;
    pb[8] = p8 * p;   pb[9] = p8 * p2;  pb[10] = p8 * p2 * p; pb[11] = p8 * p4;
    pb[12] = p8 * p4 * p; pb[13] = p8 * p4 * p2; pb[14] = p8 * p4 * p2 * p; pb[15] = p8 * p8;
}
DEV void gload_lds16(const unsigned short* g, unsigned short* l) {
    __builtin_amdgcn_global_load_lds(
        (__attribute__((address_space(1))) void*)(g),
        (__attribute__((address_space(3))) void*)(l), 16, 0, 0);
}

// ------------------------------------------------------------- f32 -> bf16
__global__ void k_cvt(const float* __restrict__ src, unsigned short* __restrict__ dst, int n) {
    int g = (blockIdx.x * 256 + threadIdx.x) * 4;
    if (g >= n) return;
    float4 v = *(const float4*)(src + g);
    ushort4 o;
    o.x = f2b(v.x); o.y = f2b(v.y); o.z = f2b(v.z); o.w = f2b(v.w);
    *(ushort4*)(dst + g) = o;
}

// ------------------------------------ xproj weights: [2][33][512] -> padded [2][48][512] bf16
__global__ void k_cvtx(const float* __restrict__ src, unsigned short* __restrict__ dst) {
    int idx = blockIdx.x * 256 + threadIdx.x;      // 2*48*512 = 49152
    int l = idx / (48 * 512), r = (idx >> 9) % 48, cc = idx & 511;
    dst[idx] = (r < 33) ? f2b(src[(size_t)(l * 33 + r) * 512 + cc]) : (unsigned short)0;
}

// --------------------------- conv weights: [2][512][4] -> transposed [2][4][512]
__global__ void k_cvtc(const float* __restrict__ src, float* __restrict__ dst) {
    int idx = blockIdx.x * 256 + threadIdx.x;      // 2*4*512 = 4096
    int l = idx >> 11, k = (idx >> 9) & 3, d = idx & 511;
    dst[idx] = src[(size_t)(l * DI + d) * 4 + k];
}

// ---------------------------------------------------------------- input proj
__global__ void k_inproj(const float* __restrict__ z, const float* __restrict__ w,
                         const float* __restrict__ bias, float* __restrict__ x) {
    int g = blockIdx.x * 256 + threadIdx.x;     // NTOK*DM threads
    int i = g >> 8, m = g & 255;
    float4 zv = *(const float4*)(z + (size_t)i * 4);
    float4 wv = *(const float4*)(w + (size_t)m * 4);
    float r = bias[m];
    r = fmaf(zv.x, wv.x, r);
    r = fmaf(zv.y, wv.y, r);
    r = fmaf(zv.z, wv.z, r);
    r = fmaf(zv.w, wv.w, r);
    x[g] = r;
}

// -------------------------------------------- fused row-LN -> bf16 (per wave)
__global__ void k_lnrow(const float* __restrict__ x, const float* __restrict__ gam,
                        const float* __restrict__ bet, unsigned short* __restrict__ xln) {
    int lane = threadIdx.x & 63, wid = threadIdx.x >> 6;
    int i = blockIdx.x * 4 + wid;
    float4 v = *(const float4*)(x + (size_t)i * DM + lane * 4);
    float s = v.x + v.y + v.z + v.w;
    float q = v.x * v.x + v.y * v.y + v.z * v.z + v.w * v.w;
    #pragma unroll
    for (int m = 32; m; m >>= 1) { s += __shfl_xor(s, m, 64); q += __shfl_xor(q, m, 64); }
    float mu = s * (1.0f / DM);
    float rs = rsqrtf(q * (1.0f / DM) - mu * mu + EPSF);
    float4 g4 = *(const float4*)(gam + lane * 4);
    float4 b4 = *(const float4*)(bet + lane * 4);
    ushort4 o;
    o.x = f2b((v.x - mu) * rs * g4.x + b4.x);
    o.y = f2b((v.y - mu) * rs * g4.y + b4.y);
    o.z = f2b((v.z - mu) * rs * g4.z + b4.z);
    o.w = f2b((v.w - mu) * rs * g4.w + b4.w);
    *(ushort4*)(xln + (size_t)i * DM + lane * 4) = o;
}

// ------------------------------------- GEMM1 (MFMA): [xp|z] = xln @ WbI^T
// M=32768 N=1024 K=256, tile 128x128, BK=32. N<512 -> xpb, else -> zbb (both bf16)
__global__ __launch_bounds__(256) void k_gemm1(
    const unsigned short* __restrict__ A, const unsigned short* __restrict__ W,
    unsigned short* __restrict__ xpb, unsigned short* __restrict__ zbb) {
    __shared__ unsigned short As[128 * 32];
    __shared__ unsigned short Bs[128 * 32];
    int tid = threadIdx.x, lane = tid & 63, wid = tid >> 6;
    int tileN = blockIdx.x & 7, tileM = blockIdx.x >> 3;
    int i0 = tileM * 128, n0 = tileN * 128;
    f32x4 acc[4][4];
    #pragma unroll
    for (int mi = 0; mi < 4; mi++)
        #pragma unroll
        for (int ni = 0; ni < 4; ni++) acc[mi][ni] = (f32x4){0.f, 0.f, 0.f, 0.f};

    int srow = (wid << 5) + (lane >> 2);
    int sblk = lane & 3;
    const unsigned short* ga = A + (size_t)(i0 + srow) * 256 + sblk * 8;
    const unsigned short* gb = W + (size_t)(n0 + srow) * 256 + sblk * 8;
    unsigned short* la = As + (wid << 5) * 32;
    unsigned short* lb = Bs + (wid << 5) * 32;
    int ar = lane & 15, ab = lane >> 4;
    const short8* pa = (const short8*)(As + ((wid >> 1) * 64 + ar) * 32 + ab * 8);
    const short8* pb = (const short8*)(Bs + ((wid & 1) * 64 + ar) * 32 + ab * 8);

    for (int k0 = 0; k0 < 256; k0 += 32) {
        gload_lds16(ga + k0,            la);
        gload_lds16(ga + k0 + 16 * 256, la + 16 * 32);
        gload_lds16(gb + k0,            lb);
        gload_lds16(gb + k0 + 16 * 256, lb + 16 * 32);
        __syncthreads();
        short8 a[4], b[4];
        #pragma unroll
        for (int mi = 0; mi < 4; mi++) a[mi] = pa[mi * 64];
        #pragma unroll
        for (int ni = 0; ni < 4; ni++) b[ni] = pb[ni * 64];
        #pragma unroll
        for (int mi = 0; mi < 4; mi++)
            #pragma unroll
            for (int ni = 0; ni < 4; ni++)
                acc[mi][ni] = __builtin_amdgcn_mfma_f32_16x16x32_bf16(a[mi], b[ni], acc[mi][ni], 0, 0, 0);
        __syncthreads();
    }
    int wr = wid >> 1, wc = wid & 1;
    int rbase = i0 + wr * 64 + (lane >> 4) * 4;
    int cbase = n0 + wc * 64 + (lane & 15);
    unsigned short* dst = (n0 < 512) ? xpb : zbb;
    int coff = (n0 < 512) ? cbase : cbase - 512;
    #pragma unroll
    for (int mi = 0; mi < 4; mi++)
        #pragma unroll
        for (int ni = 0; ni < 4; ni++)
            #pragma unroll
            for (int j = 0; j < 4; j++)
                dst[(size_t)(rbase + mi * 16 + j) * 512 + coff + ni * 16] = f2b(acc[mi][ni][j]);
}

// ---------------- depthwise causal conv + SiLU -> bf16 (rolling window, 8 tok/thread)
__global__ void k_conv(const unsigned short* __restrict__ xpb, const float* __restrict__ cwT,
                       const float* __restrict__ cb, unsigned short* __restrict__ xcb) {
    int g = blockIdx.x * 256 + threadIdx.x;     // NTOK/8 * 128 threads
    int tg = g >> 7, dq = g & 127;
    int d = dq * 4;
    int i0 = tg * 8;
    float4 w0 = *(const float4*)(cwT + 0 * DI + d);
    float4 w1 = *(const float4*)(cwT + 1 * DI + d);
    float4 w2 = *(const float4*)(cwT + 2 * DI + d);
    float4 w3 = *(const float4*)(cwT + 3 * DI + d);
    float4 bi = *(const float4*)(cb + d);
    float4 x0, x1, x2;
    if ((i0 & (SEQL - 1)) != 0) {
        x0 = b4f(*(const ushort4*)(xpb + (size_t)(i0 - 3) * DI + d));
        x1 = b4f(*(const ushort4*)(xpb + (size_t)(i0 - 2) * DI + d));
        x2 = b4f(*(const ushort4*)(xpb + (size_t)(i0 - 1) * DI + d));
    } else {
        x0 = x1 = x2 = make_float4(0.f, 0.f, 0.f, 0.f);
    }
    #pragma unroll
    for (int tt = 0; tt < 8; tt++) {
        float4 xc = b4f(*(const ushort4*)(xpb + (size_t)(i0 + tt) * DI + d));
        float4 a = bi;
        a.x = fmaf(w0.x, x0.x, a.x); a.y = fmaf(w0.y, x0.y, a.y);
        a.z = fmaf(w0.z, x0.z, a.z); a.w = fmaf(w0.w, x0.w, a.w);
        a.x = fmaf(w1.x, x1.x, a.x); a.y = fmaf(w1.y, x1.y, a.y);
        a.z = fmaf(w1.z, x1.z, a.z); a.w = fmaf(w1.w, x1.w, a.w);
        a.x = fmaf(w2.x, x2.x, a.x); a.y = fmaf(w2.y, x2.y, a.y);
        a.z = fmaf(w2.z, x2.z, a.z); a.w = fmaf(w2.w, x2.w, a.w);
        a.x = fmaf(w3.x, xc.x, a.x); a.y = fmaf(w3.y, xc.y, a.y);
        a.z = fmaf(w3.z, xc.z, a.z); a.w = fmaf(w3.w, xc.w, a.w);
        ushort4 o;
        o.x = f2b(siluf_(a.x)); o.y = f2b(siluf_(a.y));
        o.z = f2b(siluf_(a.z)); o.w = f2b(siluf_(a.w));
        *(ushort4*)(xcb + (size_t)(i0 + tt) * DI + d) = o;
        x0 = x1; x1 = x2; x2 = xc;
    }
}

// --------------------- xproj (MFMA): ssm = xcb @ WX_pad^T (N=48, rows>=33 dead)
// M=32768 N=48 K=512, tile 128x48, BK=32, 4 waves (wave w: rows w*32..w*32+31)
__global__ __launch_bounds__(256) void k_xprojm(
    const unsigned short* __restrict__ A, const unsigned short* __restrict__ W,
    float* __restrict__ Bm, float* __restrict__ Cm, float* __restrict__ dtr) {
    __shared__ unsigned short As[128 * 32];
    __shared__ unsigned short Bs[48 * 32];
    int tid = threadIdx.x, lane = tid & 63, wid = tid >> 6;
    int i0 = blockIdx.x * 128;
    f32x4 acc[2][3];
    #pragma unroll
    for (int mi = 0; mi < 2; mi++)
        #pragma unroll
        for (int ni = 0; ni < 3; ni++) acc[mi][ni] = (f32x4){0.f, 0.f, 0.f, 0.f};

    int srow = lane >> 2, sblk = lane & 3;
    const unsigned short* ga = A + (size_t)(i0 + (wid << 5) + srow) * 512 + sblk * 8;
    unsigned short* la = As + (wid << 5) * 32;
    const unsigned short* gb = W + (size_t)((wid << 4) + srow) * 512 + sblk * 8;
    unsigned short* lb = Bs + (wid << 4) * 32;
    int ar = lane & 15, ab = lane >> 4;

    for (int k0 = 0; k0 < 512; k0 += 32) {
        gload_lds16(ga + k0,            la);
        gload_lds16(ga + k0 + 16 * 512, la + 16 * 32);
        if (wid < 3) gload_lds16(gb + k0, lb);
        __syncthreads();
        short8 a[2], b[3];
        #pragma unroll
        for (int mi = 0; mi < 2; mi++)
            a[mi] = *(const short8*)(As + ((wid << 5) + mi * 16 + ar) * 32 + ab * 8);
        #pragma unroll
        for (int ni = 0; ni < 3; ni++)
            b[ni] = *(const short8*)(Bs + (ni * 16 + ar) * 32 + ab * 8);
        #pragma unroll
        for (int mi = 0; mi < 2; mi++)
            #pragma unroll
            for (int ni = 0; ni < 3; ni++)
                acc[mi][ni] = __builtin_amdgcn_mfma_f32_16x16x32_bf16(a[mi], b[ni], acc[mi][ni], 0, 0, 0);
        __syncthreads();
    }
    #pragma unroll
    for (int mi = 0; mi < 2; mi++)
        #pragma unroll
        for (int ni = 0; ni < 3; ni++)
            #pragma unroll
            for (int j = 0; j < 4; j++) {
                int row = i0 + (wid << 5) + mi * 16 + (lane >> 4) * 4 + j;
                int ng = ni * 16 + (lane & 15);
                float v = acc[mi][ni][j];
                if (ng < 16)       Bm[(size_t)row * DS + ng] = v;
                else if (ng < 32)  Cm[(size_t)row * DS + ng - 16] = v;
                else if (ng == 32) dtr[row] = v;
            }
}

// ---------------- scan phase 1: chunk-local end states only (no y)
__global__ __launch_bounds__(256) void k_scan1(
    const unsigned short* __restrict__ xcb, const float* __restrict__ Bm,
    const float* __restrict__ dtr, const float* __restrict__ dw,
    const float* __restrict__ db, float* __restrict__ hend, float* __restrict__ dtc) {
    __shared__ float Bsh[64][16];
    __shared__ float dtl[64];
    int tid = threadIdx.x;
    int blk = blockIdx.x;                       // ((b*NCH)+c)*2 + half
    int half = blk & 1, c = (blk >> 1) & (NCH - 1), b = blk >> 7;
    int d = half * 256 + tid;
    int i0 = (b << 12) + c * TC;
    if (tid < 64) dtl[tid] = dtr[i0 + tid];
    {
        int idx = tid * 4, tt = idx >> 4, ss = idx & 15;
        *(float4*)(&Bsh[tt][ss]) = *(const float4*)(Bm + (size_t)(i0 + tt) * DS + ss);
    }
    __syncthreads();
    float dwd = dw[d], dbd = db[d];
    float h[16];
    #pragma unroll
    for (int s = 0; s < 16; s++) h[s] = 0.0f;
    float dtsum = 0.0f;
    for (int t = 0; t < TC; t++) {
        float dt = softplusf_(fmaf(dtl[t], dwd, dbd));
        dtsum += dt;
        float p = __expf(-dt);
        float pb[16];
        pows16(p, pb);
        float x = b2f(xcb[(size_t)(i0 + t) * DI + d]);
        float dtx = dt * x;
        float Bv[16];
        *(float4*)(Bv + 0)  = *(const float4*)(&Bsh[t][0]);
        *(float4*)(Bv + 4)  = *(const float4*)(&Bsh[t][4]);
        *(float4*)(Bv + 8)  = *(const float4*)(&Bsh[t][8]);
        *(float4*)(Bv + 12) = *(const float4*)(&Bsh[t][12]);
        #pragma unroll
        for (int s = 0; s < 16; s++) h[s] = fmaf(pb[s], h[s], dtx * Bv[s]);
    }
    size_t hb = ((size_t)(b * DI + d) * NCH + c) * DS;
    #pragma unroll
    for (int s = 0; s < 16; s += 4)
        *(float4*)(hend + hb + s) = make_float4(h[s], h[s + 1], h[s + 2], h[s + 3]);
    dtc[(size_t)(b * DI + d) * NCH + c] = dtsum;
}

// ------------- scan phase 2: propagate chunk-entry states; thread per (b,d,s)
__global__ void k_scan2(float* __restrict__ hend, const float* __restrict__ dtc) {
    int g = blockIdx.x * 256 + threadIdx.x;     // BATCH*DI*DS = 65536
    int s = g & 15, dd = (g >> 4) & 511, b = g >> 13;
    size_t base = (size_t)(b * DI + dd) * NCH;
    float hin = 0.0f;
    float kneg = -(float)(s + 1);
    #pragma unroll 4
    for (int c = 0; c < NCH; c++) {
        size_t a = (base + c) * DS + s;
        float tmp = hend[a];
        float pb = __expf(kneg * dtc[base + c]);
        hend[a] = hin;
        hin = fmaf(pb, hin, tmp);
    }
}

// -------- scan phase 3: recompute recurrence from entry state, gate, write bf16
__global__ __launch_bounds__(256) void k_scan3(
    const unsigned short* __restrict__ xcb, const float* __restrict__ Bm,
    const float* __restrict__ Cm, const float* __restrict__ dtr,
    const float* __restrict__ dw, const float* __restrict__ db,
    const float* __restrict__ hend, const unsigned short* __restrict__ zbb,
    unsigned short* __restrict__ ygb) {
    __shared__ float Bsh[64][16];
    __shared__ float Csh[64][16];
    __shared__ float dtl[64];
    int tid = threadIdx.x;
    int blk = blockIdx.x;
    int half = blk & 1, c = (blk >> 1) & (NCH - 1), b = blk >> 7;
    int d = half * 256 + tid;
    int i0 = (b << 12) + c * TC;
    if (tid < 64) dtl[tid] = dtr[i0 + tid];
    {
        int idx = tid * 4, tt = idx >> 4, ss = idx & 15;
        *(float4*)(&Bsh[tt][ss]) = *(const float4*)(Bm + (size_t)(i0 + tt) * DS + ss);
        *(float4*)(&Csh[tt][ss]) = *(const float4*)(Cm + (size_t)(i0 + tt) * DS + ss);
    }
    __syncthreads();
    float dwd = dw[d], dbd = db[d];
    float h[16];
    size_t hb = ((size_t)(b * DI + d) * NCH + c) * DS;
    #pragma unroll
    for (int s = 0; s < 16; s += 4) *(float4*)(h + s) = *(const float4*)(hend + hb + s);
    for (int t = 0; t < TC; t++) {
        float dt = softplusf_(fmaf(dtl[t], dwd, dbd));
        float p = __expf(-dt);
        float pb[16];
        pows16(p, pb);
        size_t gi = (size_t)(i0 + t) * DI + d;
        float x = b2f(xcb[gi]);
        float dtx = dt * x;
        float Bv[16], Cv[16];
        *(float4*)(Bv + 0)  = *(const float4*)(&Bsh[t][0]);
        *(float4*)(Bv + 4)  = *(const float4*)(&Bsh[t][4]);
        *(float4*)(Bv + 8)  = *(const float4*)(&Bsh[t][8]);
        *(float4*)(Bv + 12) = *(const float4*)(&Bsh[t][12]);
        *(float4*)(Cv + 0)  = *(const float4*)(&Csh[t][0]);
        *(float4*)(Cv + 4)  = *(const float4*)(&Csh[t][4]);
        *(float4*)(Cv + 8)  = *(const float4*)(&Csh[t][8]);
        *(float4*)(Cv + 12) = *(const float4*)(&Csh[t][12]);
        float y = 0.0f;
        #pragma unroll
        for (int s = 0; s < 16; s++) {
            h[s] = fmaf(pb[s], h[s], dtx * Bv[s]);
            y = fmaf(h[s], Cv[s], y);
        }
        float z = b2f(zbb[gi]);
        ygb[gi] = f2b(y * siluf_(z));
    }
}

// ----------------------- outproj (MFMA): x += ygb @ WbO^T  (residual add)
__global__ __launch_bounds__(256) void k_outproj(
    const unsigned short* __restrict__ A, const unsigned short* __restrict__ W,
    float* __restrict__ x) {
    __shared__ unsigned short As[128 * 32];
    __shared__ unsigned short Bs[128 * 32];
    int tid = threadIdx.x, lane = tid & 63, wid = tid >> 6;
    int tileN = blockIdx.x & 1, tileM = blockIdx.x >> 1;
    int i0 = tileM * 128, n0 = tileN * 128;
    f32x4 acc[4][4];
    #pragma unroll
    for (int mi = 0; mi < 4; mi++)
        #pragma unroll
        for (int ni = 0; ni < 4; ni++) acc[mi][ni] = (f32x4){0.f, 0.f, 0.f, 0.f};

    int srow = (wid << 5) + (lane >> 2);
    int sblk = lane & 3;
    const unsigned short* ga = A + (size_t)(i0 + srow) * 512 + sblk * 8;
    const unsigned short* gb = W + (size_t)(n0 + srow) * 512 + sblk * 8;
    unsigned short* la = As + (wid << 5) * 32;
    unsigned short* lb = Bs + (wid << 5) * 32;
    int ar = lane & 15, ab = lane >> 4;
    const short8* pa = (const short8*)(As + ((wid >> 1) * 64 + ar) * 32 + ab * 8);
    const short8* pb = (const short8*)(Bs + ((wid & 1) * 64 + ar) * 32 + ab * 8);

    for (int k0 = 0; k0 < 512; k0 += 32) {
        gload_lds16(ga + k0,            la);
        gload_lds16(ga + k0 + 16 * 512, la + 16 * 32);
        gload_lds16(gb + k0,            lb);
        gload_lds16(gb + k0 + 16 * 512, lb + 16 * 32);
        __syncthreads();
        short8 a[4], b[4];
        #pragma unroll
        for (int mi = 0; mi < 4; mi++) a[mi] = pa[mi * 64];
        #pragma unroll
        for (int ni = 0; ni < 4; ni++) b[ni] = pb[ni * 64];
        #pragma unroll
        for (int mi = 0; mi < 4; mi++)
            #pragma unroll
            for (int ni = 0; ni < 4; ni++)
                acc[mi][ni] = __builtin_amdgcn_mfma_f32_16x16x32_bf16(a[mi], b[ni], acc[mi][ni], 0, 0, 0);
        __syncthreads();
    }
    int wr = wid >> 1, wc = wid & 1;
    int rbase = i0 + wr * 64 + (lane >> 4) * 4;
    int cbase = n0 + wc * 64 + (lane & 15);
    #pragma unroll
    for (int mi = 0; mi < 4; mi++)
        #pragma unroll
        for (int ni = 0; ni < 4; ni++)
            #pragma unroll
            for (int j = 0; j < 4; j++) {
                size_t idx = (size_t)(rbase + mi * 16 + j) * DM + cbase + ni * 16;
                x[idx] += acc[mi][ni][j];
            }
}

// -------------------------------------------- final LN + output projection
__global__ void k_final(const float* __restrict__ x, const float* __restrict__ gam,
                        const float* __restrict__ bet, const float* __restrict__ w,
                        const float* __restrict__ bias, float* __restrict__ out) {
    int lane = threadIdx.x & 63, wid = threadIdx.x >> 6;
    int i = blockIdx.x * 4 + wid;
    float4 v = *(const float4*)(x + (size_t)i * DM + lane * 4);
    float s = v.x + v.y + v.z + v.w;
    float q = v.x * v.x + v.y * v.y + v.z * v.z + v.w * v.w;
    #pragma unroll
    for (int m = 32; m; m >>= 1) { s += __shfl_xor(s, m, 64); q += __shfl_xor(q, m, 64); }
    float mu = s * (1.0f / DM);
    float rs = rsqrtf(q * (1.0f / DM) - mu * mu + EPSF);
    float4 gg = *(const float4*)(gam + lane * 4);
    float4 bb = *(const float4*)(bet + lane * 4);
    float xn[4] = {(v.x - mu) * rs * gg.x + bb.x, (v.y - mu) * rs * gg.y + bb.y,
                   (v.z - mu) * rs * gg.z + bb.z, (v.w - mu) * rs * gg.w + bb.w};
    float4 w0 = *(const float4*)(w + lane * 4);
    float4 w1 = *(const float4*)(w + DM + lane * 4);
    float p0 = xn[0] * w0.x + xn[1] * w0.y + xn[2] * w0.z + xn[3] * w0.w;
    float p1 = xn[0] * w1.x + xn[1] * w1.y + xn[2] * w1.z + xn[3] * w1.w;
    #pragma unroll
    for (int m = 32; m; m >>= 1) { p0 += __shfl_xor(p0, m, 64); p1 += __shfl_xor(p1, m, 64); }
    if (lane == 0) {
        out[(size_t)i * 2]     = p0 + bias[0];
        out[(size_t)i * 2 + 1] = p1 + bias[1];
    }
}

// ---------------------------------------------------------------------------
extern "C" void kernel_launch(void* const* d_in, const int* in_sizes, int n_in,
                              void* d_out, int out_size, void* d_ws, size_t ws_size,
                              hipStream_t stream) {
    const float* z_seq     = (const float*)d_in[0];
    const float* ip_w      = (const float*)d_in[1];
    const float* ip_b      = (const float*)d_in[2];
    const float* norm_g    = (const float*)d_in[3];
    const float* norm_b    = (const float*)d_in[4];
    const float* inproj_w  = (const float*)d_in[5];
    const float* conv_w    = (const float*)d_in[6];
    const float* conv_b    = (const float*)d_in[7];
    const float* xproj_w   = (const float*)d_in[8];
    const float* dt_w      = (const float*)d_in[9];
    const float* dt_b      = (const float*)d_in[10];
    const float* outproj_w = (const float*)d_in[11];
    const float* onorm_g   = (const float*)d_in[12];
    const float* onorm_b   = (const float*)d_in[13];
    const float* op_w      = (const float*)d_in[14];
    const float* op_b      = (const float*)d_in[15];

    char* ws = (char*)d_ws;
    float* x    = (float*)(ws + OFF_X);
    unsigned short* xpb = (unsigned short*)(ws + OFF_XPB);
    unsigned short* zbb = (unsigned short*)(ws + OFF_ZBB);
    unsigned short* xcb = (unsigned short*)(ws + OFF_XCB);
    unsigned short* xln = (unsigned short*)(ws + OFF_XLN);
    float* Bmb  = (float*)(ws + OFF_B);
    float* Cmb  = (float*)(ws + OFF_C);
    float* dtrb = (float*)(ws + OFF_DTR);
    float* hend = (float*)(ws + OFF_HE);
    float* dtc  = (float*)(ws + OFF_DTC);
    unsigned short* WbI = (unsigned short*)(ws + OFF_WBI);
    unsigned short* WbO = (unsigned short*)(ws + OFF_WBO);
    unsigned short* WbX = (unsigned short*)(ws + OFF_WBX);
    float* cwT  = (float*)(ws + OFF_CWT);

    k_cvt<<<(int)(WBI_EL / 4 / 256), 256, 0, stream>>>(inproj_w,  WbI, (int)WBI_EL);
    k_cvt<<<(int)(WBO_EL / 4 / 256), 256, 0, stream>>>(outproj_w, WbO, (int)WBO_EL);
    k_cvtx<<<2 * 48 * 512 / 256, 256, 0, stream>>>(xproj_w, WbX);
    k_cvtc<<<2 * 4 * 512 / 256, 256, 0, stream>>>(conv_w, cwT);

    k_inproj<<<NTOK * DM / 256, 256, 0, stream>>>(z_seq, ip_w, ip_b, x);

    for (int l = 0; l < 2; l++) {
        k_lnrow<<<NTOK / 4, 256, 0, stream>>>(x, norm_g + l * DM, norm_b + l * DM, xln);
        k_gemm1<<<(NTOK / 128) * 8, 256, 0, stream>>>(
            xln, WbI + (size_t)l * 2 * DI * DM, xpb, zbb);
        k_conv<<<(NTOK / 8) * 128 / 256, 256, 0, stream>>>(
            xpb, cwT + (size_t)l * 4 * DI, conv_b + (size_t)l * DI, xcb);
        k_xprojm<<<NTOK / 128, 256, 0, stream>>>(
            xcb, WbX + (size_t)l * 48 * DI, Bmb, Cmb, dtrb);
        k_scan1<<<BATCH * NCH * 2, 256, 0, stream>>>(
            xcb, Bmb, dtrb, dt_w + l * DI, dt_b + l * DI, hend, dtc);
        k_scan2<<<BATCH * DI * DS / 256, 256, 0, stream>>>(hend, dtc);
        k_scan3<<<BATCH * NCH * 2, 256, 0, stream>>>(
            xcb, Bmb, Cmb, dtrb, dt_w + l * DI, dt_b + l * DI, hend, zbb, xpb);
        k_outproj<<<(NTOK / 128) * 2, 256, 0, stream>>>(
            xpb, WbO + (size_t)l * DM * DI, x);
    }
    k_final<<<NTOK / 4, 256, 0, stream>>>(x, onorm_g, onorm_b, op_w, op_b, (float*)d_out);
}